// Round 13
// baseline (333.119 us; speedup 1.0000x reference)
//
#include <hip/hip_runtime.h>
#include <hip/hip_fp16.h>
#include <math.h>

#define B 8
#define C 256
#define L 4096
#define OC3 768

typedef __attribute__((ext_vector_type(8))) short short8v;
typedef __attribute__((ext_vector_type(8))) unsigned short u16x8;
typedef __attribute__((ext_vector_type(4))) float f32x4;

// ---------------- helpers ----------------
__device__ __forceinline__ float gelu_exact(float x){
  return 0.5f * x * (1.0f + erff(x * 0.70710678118654752440f));
}
__device__ __forceinline__ float wave_sum(float v){
  #pragma unroll
  for (int off = 32; off > 0; off >>= 1) v += __shfl_down(v, off, 64);
  return v;
}
__device__ __forceinline__ unsigned short f16b(float f){
  return __half_as_ushort(__float2half_rn(f));
}
__device__ __forceinline__ float f16tof(unsigned short u){
  return __half2float(__ushort_as_half(u));
}
__device__ __forceinline__ unsigned int splitpackh(float v){
  unsigned short hi = f16b(v);
  float lof = v - f16tof(hi);
  unsigned short lo = f16b(lof);
  return (unsigned int)hi | ((unsigned int)lo << 16);
}
// async global->LDS 16B per lane; LDS dest must be wave-uniform base
__device__ __forceinline__ void gl16(const unsigned short* g, unsigned short* l){
  __builtin_amdgcn_global_load_lds(
      (const __attribute__((address_space(1))) void*)g,
      (__attribute__((address_space(3))) void*)l, 16, 0, 0);
}

// ---------------- weight split ----------------
// Wf16 region (shorts): qkv@0 (196608), gate@196608, down@262144, up@294912,
// projH@327680, projL@393216   (proj stored as f16 hi/lo pair)
__global__ __launch_bounds__(256) void wsplit_kernel(
    const float* __restrict__ wqkv, const float* __restrict__ wgate,
    const float* __restrict__ wdown, const float* __restrict__ wup,
    const float* __restrict__ wproj,
    unsigned short* __restrict__ Wf16,
    unsigned short* __restrict__ PH, unsigned short* __restrict__ PLo)
{
  int idx = blockIdx.x * 256 + threadIdx.x;   // 0..393215
  if (idx < 327680) {
    float s;
    if (idx < 196608)      s = wqkv[idx];
    else if (idx < 262144) s = wgate[idx - 196608];
    else if (idx < 294912) s = wdown[idx - 262144];
    else                   s = wup[idx - 294912];
    Wf16[idx] = f16b(s);
  } else {
    int j = idx - 327680;
    float wv = wproj[j];
    unsigned short hh = f16b(wv);
    PH[j]  = hh;
    PLo[j] = f16b(wv - f16tof(hh));
  }
}

// ---------------- x [b][c][l] fp32 -> xT hi/lo f16 [b][l][c] ----------------
__global__ __launch_bounds__(256) void splitx_kernel(const float* __restrict__ x,
    unsigned short* __restrict__ XThi, unsigned short* __restrict__ XTlo)
{
  __shared__ float st[64][68];
  const int b = blockIdx.z, c0 = blockIdx.y * 64, lb = blockIdx.x * 64;
  const int t = threadIdx.x;
  #pragma unroll
  for (int i = 0; i < 4; i++) {
    int row = (t >> 4) + i * 16;
    int col = (t & 15) * 4;
    float4 v = *(const float4*)&x[((size_t)b * C + c0 + row) * L + lb + col];
    st[row][col] = v.x; st[row][col+1] = v.y; st[row][col+2] = v.z; st[row][col+3] = v.w;
  }
  __syncthreads();
  const int l = t >> 2, cq = t & 3;
  u16x8 hv0, hv1, lv0, lv1;
  #pragma unroll
  for (int i = 0; i < 16; i++) {
    unsigned int p = splitpackh(st[cq * 16 + i][l]);
    if (i < 8) { hv0[i] = (unsigned short)(p & 0xFFFFu); lv0[i] = (unsigned short)(p >> 16); }
    else       { hv1[i-8] = (unsigned short)(p & 0xFFFFu); lv1[i-8] = (unsigned short)(p >> 16); }
  }
  size_t o = ((size_t)b * L + lb + l) * C + c0 + cq * 16;
  *(u16x8*)&XThi[o]     = hv0;
  *(u16x8*)&XThi[o + 8] = hv1;
  *(u16x8*)&XTlo[o]     = lv0;
  *(u16x8*)&XTlo[o + 8] = lv1;
}

// ---------------- f16 MFMA GEMM (qkv only), 2-phase double-buffered ----------------
template<int KTOT, int EPI, int MODE>
__global__ __launch_bounds__(256) void hgemm(
    const unsigned short* __restrict__ Ahi_g, const unsigned short* __restrict__ Alo_g,
    const unsigned short* __restrict__ Bw_g,
    float* __restrict__ outF,
    unsigned short* __restrict__ outH,
    int Ntot)
{
  __shared__ unsigned short SB[2][3][128 * 32];
  const int t  = threadIdx.x;
  const int lb = blockIdx.x * 128;
  const int o0 = blockIdx.y * 128;
  const int b  = blockIdx.z;
  const int w  = t >> 6, lane = t & 63;
  const int wm = w >> 1, wn = w & 1;
  const int ln = lane & 15, lg = lane >> 4;
  const int lrow  = lane >> 2;
  const int chunk = (lane & 3) ^ ((lane >> 4) & 3);
  const int slot  = lg ^ (ln >> 2);
  const bool twop = (blockIdx.y < 2);

  f32x4 z4 = {0.f, 0.f, 0.f, 0.f};
  f32x4 acc[4][4];
  #pragma unroll
  for (int i = 0; i < 4; i++)
    #pragma unroll
    for (int j = 0; j < 4; j++) acc[i][j] = z4;

  const size_t arow0 = (size_t)b * L + lb;
  constexpr int NKT = KTOT / 32;

  auto stage = [&](int kt, int cb) {
    const int k0 = kt * 32;
    #pragma unroll
    for (int i = 0; i < 2; i++) {
      const int rb = w * 32 + i * 16;
      const size_t ga = (arow0 + rb + lrow) * KTOT + k0 + chunk * 8;
      gl16(Ahi_g + ga, &SB[cb][0][rb * 32]);
      if (twop) gl16(Alo_g + ga, &SB[cb][1][rb * 32]);
      const size_t gb = (size_t)(o0 + rb + lrow) * KTOT + k0 + chunk * 8;
      gl16(Bw_g + gb, &SB[cb][2][rb * 32]);
    }
  };

  stage(0, 0);
  __syncthreads();
  int cur = 0;
  for (int kt = 0; kt < NKT; ++kt) {
    if (kt + 1 < NKT) stage(kt + 1, cur ^ 1);
    short8v bwf[4];
    #pragma unroll
    for (int nf = 0; nf < 4; nf++) {
      const int off = (wn * 64 + nf * 16 + ln) * 32 + slot * 8;
      bwf[nf] = *(const short8v*)&SB[cur][2][off];
    }
    #pragma unroll
    for (int mf = 0; mf < 4; mf++) {
      const int off = (wm * 64 + mf * 16 + ln) * 32 + slot * 8;
      const short8v ah = *(const short8v*)&SB[cur][0][off];
      #pragma unroll
      for (int nf = 0; nf < 4; nf++)
        acc[mf][nf] = __builtin_amdgcn_mfma_f32_16x16x32_f16(ah, bwf[nf], acc[mf][nf], 0, 0, 0);
      if (twop) {
        const short8v al = *(const short8v*)&SB[cur][1][off];
        #pragma unroll
        for (int nf = 0; nf < 4; nf++)
          acc[mf][nf] = __builtin_amdgcn_mfma_f32_16x16x32_f16(al, bwf[nf], acc[mf][nf], 0, 0, 0);
      }
    }
    __syncthreads();
    cur ^= 1;
  }
  #pragma unroll
  for (int mf = 0; mf < 4; mf++) {
    const int mbase = lb + wm * 64 + mf * 16 + lg * 4;
    #pragma unroll
    for (int nf = 0; nf < 4; nf++) {
      const int o = o0 + wn * 64 + nf * 16 + ln;
      if (o0 < 256) {
        float4 r;
        r.x = acc[mf][nf][0]; r.y = acc[mf][nf][1];
        r.z = acc[mf][nf][2]; r.w = acc[mf][nf][3];
        *(float4*)&outF[((size_t)b * 256 + o) * L + mbase] = r;
      } else {
        ushort4 r;
        r.x = f16b(acc[mf][nf][0]); r.y = f16b(acc[mf][nf][1]);
        r.z = f16b(acc[mf][nf][2]); r.w = f16b(acc[mf][nf][3]);
        *(ushort4*)&outH[((size_t)b * 512 + (o - 256)) * L + mbase] = r;
      }
    }
  }
}

// ---------------- FUSED MLP + PROJ v4: 64-stage counted-vmcnt pipeline ----------------
// 64 l-rows/block; zL+mL accesses wave-local; weight tiles [64o][64k] stream through
// wL[4] with: issue p_{s+2} -> s_waitcnt vmcnt(4) (own p_s drained) -> s_barrier ->
// compute p_s. Loads for p_{s+1},p_{s+2} stay in flight across barriers (T4).
// Stage table: gate s0-15, down s16-23, up s24-31 (reads mL), proj s32-63 (H/L pair).
struct SDesc { unsigned int woff; int stride; int acc; int cbase; int isM; };
__device__ __forceinline__ SDesc sdesc(int s){
  if (s < 16) { int rg = s >> 2, kc = s & 3;
    SDesc d = {196608u + (unsigned)(rg * 64 * 256 + kc * 64), 256, rg, kc * 8, 0}; return d; }
  if (s < 24) { int i = s - 16; int rg = i >> 2, kc = i & 3;
    SDesc d = {262144u + (unsigned)(rg * 64 * 256 + kc * 64), 256, rg, kc * 8, 0}; return d; }
  if (s < 32) { int i = s - 24; int rg = i >> 1, kc = i & 1;
    SDesc d = {294912u + (unsigned)(rg * 64 * 128 + kc * 64), 128, rg, kc * 8, 1}; return d; }
  int i = s - 32; int rg = i >> 3, pl = (i >> 2) & 1, kc = i & 3;
  SDesc d = {(pl ? 393216u : 327680u) + (unsigned)(rg * 64 * 256 + kc * 64), 256, rg, kc * 8, 0};
  return d;
}

__global__ __launch_bounds__(256, 2) void mlp_fused_kernel(
    const unsigned short* __restrict__ zT,     // [b][l][256] f16
    const unsigned short* __restrict__ outT,   // [b][l][256] f16
    const unsigned short* __restrict__ Wmega,  // region C base (Wf16)
    const float* __restrict__ bg, const float* __restrict__ bd, const float* __restrict__ bu,
    float* __restrict__ out0)                  // [b][256][L] fp32
{
  __shared__ unsigned short zL[64 * 256];      // 32KB
  __shared__ unsigned short wL[4][64 * 64];    // 4 x 8KB
  unsigned short* mL = zL;                     // [64][128] alias (barrier-guarded)
  const int t = threadIdx.x;
  const int l0 = blockIdx.x * 64;
  const int b  = blockIdx.y;
  const int w = t >> 6, lane = t & 63;
  const int ln = lane & 15, lg = lane >> 4;

  // ---- z tile: wave-local rows, pre-swizzled source, linear gl16 dest (8 gl16/wave) ----
  {
    const int rIn = lane >> 5, ch = lane & 31;
    #pragma unroll
    for (int j = 0; j < 8; j++) {
      const int rowbase = w * 16 + j * 2;
      const int row = rowbase + rIn;
      const int sc = ch ^ (row & 7);
      gl16(zT + ((size_t)b * L + l0 + row) * 256 + sc * 8, &zL[rowbase * 256]);
    }
  }
  // issue one [64][64] weight tile into wL[cb] (2 gl16/wave)
  auto issueW = [&](int cb, unsigned int woff, int stride) {
    const int rIn = lane >> 3, ch = lane & 7;
    #pragma unroll
    for (int j = 0; j < 2; j++) {
      const int rowbase = w * 16 + j * 8;
      const int row = rowbase + rIn;
      const int sc = ch ^ (row & 7);
      gl16(Wmega + (size_t)woff + (size_t)row * stride + sc * 8, &wL[cb][rowbase * 64]);
    }
  };
  auto fragZ = [&](int row, int cc) -> short8v {
    return *(const short8v*)&zL[row * 256 + (cc ^ (row & 7)) * 8];
  };
  auto fragW = [&](int cb, int row, int cc) -> short8v {
    return *(const short8v*)&wL[cb][row * 64 + (cc ^ (row & 7)) * 8];
  };
  auto fragM = [&](int row, int cc) -> short8v {
    return *(const short8v*)&mL[row * 128 + (cc ^ (row & 7)) * 8];
  };

  const f32x4 zz = {0.f, 0.f, 0.f, 0.f};
  f32x4 acc[4][4];
  #pragma unroll
  for (int i = 0; i < 4; i++)
    #pragma unroll
    for (int j = 0; j < 4; j++) acc[i][j] = zz;

  // prologue: issue p0 -> buf0, p1 -> buf1
  { SDesc d = sdesc(0); issueW(0, d.woff, d.stride); }
  { SDesc d = sdesc(1); issueW(1, d.woff, d.stride); }

  #pragma unroll
  for (int s = 0; s < 64; ++s) {
    if (s + 2 < 64) { SDesc d2 = sdesc(s + 2); issueW((s + 2) & 3, d2.woff, d2.stride); }
    if (s <= 61)      asm volatile("s_waitcnt vmcnt(4)" ::: "memory");
    else if (s == 62) asm volatile("s_waitcnt vmcnt(2)" ::: "memory");
    else              asm volatile("s_waitcnt vmcnt(0)" ::: "memory");
    __builtin_amdgcn_sched_barrier(0);
    __builtin_amdgcn_s_barrier();
    __builtin_amdgcn_sched_barrier(0);
    {
      SDesc d = sdesc(s);
      const int buf = s & 3;
      if (d.isM) {
        #pragma unroll
        for (int ks = 0; ks < 2; ks++) {
          const short8v af = fragM(w * 16 + ln, d.cbase + ks * 4 + lg);
          #pragma unroll
          for (int nf = 0; nf < 4; nf++) {
            const short8v bf = fragW(buf, nf * 16 + ln, ks * 4 + lg);
            acc[d.acc][nf] = __builtin_amdgcn_mfma_f32_16x16x32_f16(af, bf, acc[d.acc][nf], 0, 0, 0);
          }
        }
      } else {
        #pragma unroll
        for (int ks = 0; ks < 2; ks++) {
          const short8v af = fragZ(w * 16 + ln, d.cbase + ks * 4 + lg);
          #pragma unroll
          for (int nf = 0; nf < 4; nf++) {
            const short8v bf = fragW(buf, nf * 16 + ln, ks * 4 + lg);
            acc[d.acc][nf] = __builtin_amdgcn_mfma_f32_16x16x32_f16(af, bf, acc[d.acc][nf], 0, 0, 0);
          }
        }
      }
    }
    if (s == 15) {
      // gate epilogue: gated = gelu(acc+bg)*z, overwrite zL (wave-local rows, no barrier)
      #pragma unroll
      for (int oc = 0; oc < 4; oc++)
        #pragma unroll
        for (int nf = 0; nf < 4; nf++)
          #pragma unroll
          for (int r = 0; r < 4; r++) {
            const int l = w * 16 + lg * 4 + r;
            const int o = oc * 64 + nf * 16 + ln;
            const int a = l * 256 + (((o >> 3) ^ (l & 7)) << 3) + (o & 7);
            zL[a] = f16b(gelu_exact(acc[oc][nf][r] + bg[o]) * f16tof(zL[a]));
          }
      #pragma unroll
      for (int i = 0; i < 4; i++)
        #pragma unroll
        for (int j = 0; j < 4; j++) acc[i][j] = zz;
    }
    if (s == 23) {
      __syncthreads();   // all gated reads done before mL (zL-alias) writes
      #pragma unroll
      for (int oc = 0; oc < 2; oc++)
        #pragma unroll
        for (int nf = 0; nf < 4; nf++)
          #pragma unroll
          for (int r = 0; r < 4; r++) {
            const int l = w * 16 + lg * 4 + r;
            const int o = oc * 64 + nf * 16 + ln;
            mL[l * 128 + (((o >> 3) ^ (l & 7)) << 3) + (o & 7)] = f16b(acc[oc][nf][r] + bd[o]);
          }
      #pragma unroll
      for (int i = 0; i < 4; i++)
        #pragma unroll
        for (int j = 0; j < 4; j++) acc[i][j] = zz;
    }
    if (s == 31) {
      __syncthreads();   // all mL reads done before preproj (zL) writes clobber alias
      #pragma unroll
      for (int oc = 0; oc < 4; oc++)
        #pragma unroll
        for (int nf = 0; nf < 4; nf++)
          #pragma unroll
          for (int r = 0; r < 4; r++) {
            const int l = w * 16 + lg * 4 + r;
            const int o = oc * 64 + nf * 16 + ln;
            const float v = acc[oc][nf][r] + bu[o]
                          + f16tof(outT[((size_t)b * L + l0 + l) * 256 + o]);
            zL[l * 256 + (((o >> 3) ^ (l & 7)) << 3) + (o & 7)] = f16b(v);
          }
      #pragma unroll
      for (int i = 0; i < 4; i++)
        #pragma unroll
        for (int j = 0; j < 4; j++) acc[i][j] = zz;
    }
  }
  // proj write
  #pragma unroll
  for (int oc = 0; oc < 4; oc++)
    #pragma unroll
    for (int nf = 0; nf < 4; nf++) {
      const int o = oc * 64 + nf * 16 + ln;
      float4 r4;
      r4.x = acc[oc][nf][0]; r4.y = acc[oc][nf][1];
      r4.z = acc[oc][nf][2]; r4.w = acc[oc][nf][3];
      *(float4*)&out0[((size_t)b * 256 + o) * L + l0 + w * 16 + lg * 4] = r4;
    }
}

// ---------------- depthwise 3x3 conv: q from fp32, k/v from f16; out single f16 ----------------
__global__ __launch_bounds__(256) void dwconv2_kernel(
    const float* __restrict__ inQ, const unsigned short* __restrict__ inKV,
    const float* __restrict__ wdw,
    unsigned short* __restrict__ qkF, unsigned short* __restrict__ vF,
    float* __restrict__ csum, float* __restrict__ csumsq)
{
  __shared__ float p[66][73];
  __shared__ float rs[4][2];
  const int ch = blockIdx.x;
  const int b  = blockIdx.y;
  const int t  = threadIdx.x;
  float wt[9];
  #pragma unroll
  for (int j = 0; j < 9; j++) wt[j] = wdw[ch * 9 + j];
  if (t < 66) { p[0][3 + t] = 0.f; p[65][3 + t] = 0.f; }
  if (t < 64) { p[1 + t][3] = 0.f; p[1 + t][68] = 0.f; }
  if (ch < 256) {
    const size_t base = ((size_t)b * 256 + ch) * L;
    #pragma unroll
    for (int i = 0; i < 4; i++) {
      int pix = (i * 256 + t) * 4;
      const float4 v = *reinterpret_cast<const float4*>(&inQ[base + pix]);
      int h = pix >> 6, ww = pix & 63;
      p[1+h][4+ww] = v.x; p[1+h][5+ww] = v.y; p[1+h][6+ww] = v.z; p[1+h][7+ww] = v.w;
    }
  } else {
    const size_t base = ((size_t)b * 512 + (ch - 256)) * L + t * 16;
    const u16x8 a0 = *(const u16x8*)&inKV[base];
    const u16x8 a1 = *(const u16x8*)&inKV[base + 8];
    const int h = t >> 2, w0 = (t & 3) * 16;
    #pragma unroll
    for (int j = 0; j < 8; j++) {
      p[1+h][4+w0+j]   = f16tof((unsigned short)a0[j]);
      p[1+h][12+w0+j]  = f16tof((unsigned short)a1[j]);
    }
  }
  __syncthreads();
  const int h  = t >> 2;
  const int w0 = (t & 3) * 16;
  float r0a[18], r1a[18], r2a[18];
  #pragma unroll
  for (int c = 0; c < 18; c++) {
    r0a[c] = p[h][w0 + 3 + c];
    r1a[c] = p[h + 1][w0 + 3 + c];
    r2a[c] = p[h + 2][w0 + 3 + c];
  }
  float res[16];
  float s = 0.f, s2 = 0.f;
  #pragma unroll
  for (int j = 0; j < 16; j++) {
    float acc;
    acc = r0a[j] * wt[0];
    acc = fmaf(r0a[j+1], wt[1], acc);
    acc = fmaf(r0a[j+2], wt[2], acc);
    acc = fmaf(r1a[j],   wt[3], acc);
    acc = fmaf(r1a[j+1], wt[4], acc);
    acc = fmaf(r1a[j+2], wt[5], acc);
    acc = fmaf(r2a[j],   wt[6], acc);
    acc = fmaf(r2a[j+1], wt[7], acc);
    acc = fmaf(r2a[j+2], wt[8], acc);
    res[j] = acc;
    s += acc;
    s2 = fmaf(acc, acc, s2);
  }
  u16x8 h0v, h1v;
  #pragma unroll
  for (int j = 0; j < 16; j++) {
    if (j < 8) h0v[j]   = f16b(res[j]);
    else       h1v[j-8] = f16b(res[j]);
  }
  if (ch < 512) {
    const size_t qi = ((size_t)b * 512 + ch) * L + t * 16;
    *(u16x8*)&qkF[qi]     = h0v;
    *(u16x8*)&qkF[qi + 8] = h1v;
    s = wave_sum(s); s2 = wave_sum(s2);
    const int lane = t & 63, wid = t >> 6;
    if (lane == 0) { rs[wid][0] = s; rs[wid][1] = s2; }
    __syncthreads();
    if (t == 0) {
      csum[b * 512 + ch]   = rs[0][0] + rs[1][0] + rs[2][0] + rs[3][0];
      csumsq[b * 512 + ch] = rs[0][1] + rs[1][1] + rs[2][1] + rs[3][1];
    }
  } else {
    const size_t vi = ((size_t)b * 256 + (ch - 512)) * L + t * 16;
    *(u16x8*)&vF[vi]     = h0v;
    *(u16x8*)&vF[vi + 8] = h1v;
  }
}

// ---------------- rank (stable descending) + sorted stats ----------------
__global__ __launch_bounds__(256) void rankstats_kernel(
    const float* __restrict__ csum, const float* __restrict__ csumsq,
    int* __restrict__ order,
    float* __restrict__ sumq, float* __restrict__ sumk,
    float* __restrict__ invnq, float* __restrict__ invnk)
{
  const int c = threadIdx.x;
  float key = 0.f;
  #pragma unroll
  for (int b = 0; b < 8; b++) key += csum[b * 512 + c];
  __shared__ float keys[256];
  __shared__ int ordS[256];
  keys[c] = key;
  __syncthreads();
  int rank = 0;
  for (int j = 0; j < 256; j++) {
    float kj = keys[j];
    rank += (kj > key) || (kj == key && j < c);
  }
  order[rank] = c;
  ordS[rank] = c;
  __syncthreads();
  const int ch = ordS[c];
  #pragma unroll
  for (int b = 0; b < 8; b++) {
    sumq[b * 256 + c]  = csum[b * 512 + ch];
    invnq[b * 256 + c] = 1.0f / fmaxf(sqrtf(csumsq[b * 512 + ch]), 1e-12f);
    sumk[b * 256 + c]  = csum[b * 512 + 256 + ch];
    invnk[b * 256 + c] = 1.0f / fmaxf(sqrtf(csumsq[b * 512 + 256 + ch]), 1e-12f);
  }
}

// ---------------- pack: vTS = v^T sorted (f16) [b][l][r]; zqT = qn+kn (f16) [b][l][r] ----------------
__global__ __launch_bounds__(256) void vpack_kernel(
    const unsigned short* __restrict__ vF, const unsigned short* __restrict__ qkF,
    const int* __restrict__ order,
    const float* __restrict__ invnq, const float* __restrict__ invnk,
    unsigned short* __restrict__ vTS, unsigned short* __restrict__ zqT)
{
  __shared__ float vt[64][65];
  __shared__ float zt[64][65];
  __shared__ int   ordS[256];
  __shared__ float iqS[256], ikS[256];
  const int t = threadIdx.x, lb = blockIdx.x * 64, b = blockIdx.y;
  ordS[t] = order[t];
  iqS[t] = invnq[b * 256 + t];
  ikS[t] = invnk[b * 256 + t];
  __syncthreads();
  for (int cc = 0; cc < 4; cc++) {
    const int r0 = cc * 64;
    for (int i = t; i < 1024; i += 256) {
      const int row = i >> 4, q = i & 15;
      const int ch = ordS[r0 + row];
      const float iq = iqS[r0 + row], ik = ikS[r0 + row];
      const ushort4 v4 = *(const ushort4*)&vF[((size_t)b * 256 + ch) * L + lb + q * 4];
      vt[q*4+0][row] = f16tof(v4.x); vt[q*4+1][row] = f16tof(v4.y);
      vt[q*4+2][row] = f16tof(v4.z); vt[q*4+3][row] = f16tof(v4.w);
      const ushort4 q4 = *(const ushort4*)&qkF[((size_t)b * 512 + ch) * L + lb + q * 4];
      const ushort4 k4 = *(const ushort4*)&qkF[((size_t)b * 512 + 256 + ch) * L + lb + q * 4];
      zt[q*4+0][row] = f16tof(q4.x) * iq + f16tof(k4.x) * ik;
      zt[q*4+1][row] = f16tof(q4.y) * iq + f16tof(k4.y) * ik;
      zt[q*4+2][row] = f16tof(q4.z) * iq + f16tof(k4.z) * ik;
      zt[q*4+3][row] = f16tof(q4.w) * iq + f16tof(k4.w) * ik;
    }
    __syncthreads();
    const int l = t >> 2, qq = t & 3;
    const size_t ob = ((size_t)b * L + lb + l) * 256 + r0 + qq * 16;
    u16x8 vv[2], zz[2];
    #pragma unroll
    for (int j = 0; j < 16; j++) {
      vv[j>>3][j&7] = f16b(vt[l][qq*16 + j]);
      zz[j>>3][j&7] = f16b(zt[l][qq*16 + j]);
    }
    *(u16x8*)&vTS[ob]     = vv[0]; *(u16x8*)&vTS[ob + 8] = vv[1];
    *(u16x8*)&zqT[ob]     = zz[0]; *(u16x8*)&zqT[ob + 8] = zz[1];
    __syncthreads();
  }
}

// ---------------- scores via 1-pass f16 MFMA, 2-phase gather staging ----------------
template<int G, int GI, int START, int MB, int SPB>
__device__ void scores_body(const unsigned short* __restrict__ qkF,
    const int* __restrict__ order, float* __restrict__ Spart,
    unsigned short* Ah, unsigned short* Bh, int* ordS)
{
  constexpr int MR = (G - MB * 64 < 64) ? (G - MB * 64) : 64;
  constexpr int NF = G / 16;
  const int t = threadIdx.x, ks = blockIdx.x, b = blockIdx.y;
  const int w = t >> 6, lane = t & 63, ln = lane & 15, lg = lane >> 4;
  const int lrow  = lane >> 2;
  const int chunk = (lane & 3) ^ ((lane >> 4) & 3);
  const int slot  = lg ^ (ln >> 2);
  for (int i = t; i < G; i += 256) ordS[i] = order[START + i];
  __syncthreads();
  const int k0 = ks * 512;
  const bool act = (w * 16) < MR;
  f32x4 z4 = {0.f, 0.f, 0.f, 0.f};
  f32x4 acc[NF];
  #pragma unroll
  for (int i = 0; i < NF; i++) acc[i] = z4;

  auto stage = [&](int kc, int cb) {
    for (int i = w; i < MR / 16; i += 4) {
      const int rb = i * 16;
      const int ch = ordS[MB * 64 + rb + lrow];
      const size_t g = ((size_t)b * 512 + ch) * L + k0 + kc + chunk * 8;
      gl16(qkF + g, &Ah[cb * 2048 + rb * 32]);
    }
    for (int i = w; i < G / 16; i += 4) {
      const int rb = i * 16;
      const int ch = 256 + ordS[rb + lrow];
      const size_t g = ((size_t)b * 512 + ch) * L + k0 + kc + chunk * 8;
      gl16(qkF + g, &Bh[cb * 3072 + rb * 32]);
    }
  };

  stage(0, 0);
  __syncthreads();
  int cur = 0;
  for (int kc = 0; kc < 512; kc += 32) {
    if (kc + 32 < 512) stage(kc + 32, cur ^ 1);
    if (act) {
      const int aoff = cur * 2048 + (w * 16 + ln) * 32 + slot * 8;
      const short8v ah = *(const short8v*)&Ah[aoff];
      #pragma unroll
      for (int nf = 0; nf < NF; nf++) {
        const int boff = cur * 3072 + (nf * 16 + ln) * 32 + slot * 8;
        const short8v bh = *(const short8v*)&Bh[boff];
        acc[nf] = __builtin_amdgcn_mfma_f32_16x16x32_f16(ah, bh, acc[nf], 0, 0, 0);
      }
    }
    __syncthreads();
    cur ^= 1;
  }
  if (act) {
    float* dst = Spart + (size_t)b * 147456 + SPB + ks * G * G;
    #pragma unroll
    for (int nf = 0; nf < NF; nf++) {
      const int d = nf * 16 + ln;
      #pragma unroll
      for (int r = 0; r < 4; r++) {
        const int m = MB * 64 + w * 16 + lg * 4 + r;
        dst[m * G + d] = acc[nf][r];
      }
    }
  }
}

__global__ __launch_bounds__(256) void scores_kernel(const unsigned short* __restrict__ qkF,
    const int* __restrict__ order, float* __restrict__ Spart)
{
  __shared__ unsigned short Ah[2 * 64 * 32];
  __shared__ unsigned short Bh[2 * 96 * 32];
  __shared__ int ordS[96];
  switch (blockIdx.z) {
    case 0:  scores_body<32, 0, 0,   0, 0    >(qkF, order, Spart, Ah, Bh, ordS); break;
    case 1:  scores_body<64, 1, 32,  0, 8192 >(qkF, order, Spart, Ah, Bh, ordS); break;
    case 2:  scores_body<64, 2, 96,  0, 40960>(qkF, order, Spart, Ah, Bh, ordS); break;
    case 3:  scores_body<96, 3, 160, 0, 73728>(qkF, order, Spart, Ah, Bh, ordS); break;
    default: scores_body<96, 3, 160, 1, 73728>(qkF, order, Spart, Ah, Bh, ordS); break;
  }
}

// ---------------- reduce partials, scale, wave-parallel softmax -> single f16 attn ----------------
template<int G, int GI, int START, int SPB, int AOFF>
__device__ void softmax_body(const float* __restrict__ Spart, const float* __restrict__ invnq,
    const float* __restrict__ invnk, const float* __restrict__ temperature,
    unsigned short* __restrict__ attnP, float* Sm)
{
  constexpr int RQ = G / 4;
  const int t = threadIdx.x;
  const int b = blockIdx.x;
  const int r0 = blockIdx.z * RQ;
  const float temp = temperature[GI];
  for (int idx = t; idx < RQ * G; idx += 256) {
    const int rl = idx / G, d = idx - rl * G;
    const int gidx = (r0 + rl) * G + d;
    float s = 0.f;
    #pragma unroll
    for (int ks = 0; ks < 8; ks++)
      s += Spart[(size_t)b * 147456 + SPB + ks * G * G + gidx];
    Sm[idx] = s * invnq[b * 256 + START + r0 + rl] * invnk[b * 256 + START + d] * temp;
  }
  __syncthreads();
  const int wv = t >> 6, lane = t & 63;
  for (int r = wv; r < RQ; r += 4) {
    const float v0 = (lane < G) ? Sm[r * G + lane] : -INFINITY;
    const float v1 = (64 + lane < G) ? Sm[r * G + 64 + lane] : -INFINITY;
    float m = fmaxf(v0, v1);
    #pragma unroll
    for (int off = 32; off > 0; off >>= 1) m = fmaxf(m, __shfl_xor(m, off, 64));
    const float e0 = (lane < G) ? expf(v0 - m) : 0.f;
    const float e1 = (64 + lane < G) ? expf(v1 - m) : 0.f;
    float s = e0 + e1;
    #pragma unroll
    for (int off = 32; off > 0; off >>= 1) s += __shfl_xor(s, off, 64);
    const float inv = 1.0f / s;
    const size_t base = (size_t)b * 18432 + AOFF + (size_t)(r0 + r) * G;
    if (lane < G)      attnP[base + lane]      = f16b(e0 * inv);
    if (64 + lane < G) attnP[base + 64 + lane] = f16b(e1 * inv);
  }
}

__global__ __launch_bounds__(256) void softmax_kernel(const float* __restrict__ Spart,
    const float* __restrict__ invnq, const float* __restrict__ invnk,
    const float* __restrict__ temperature, unsigned short* __restrict__ attnP)
{
  extern __shared__ float smem[];
  switch (blockIdx.y) {
    case 0:  softmax_body<32, 0, 0,   0,     0   >(Spart, invnq, invnk, temperature, attnP, smem); break;
    case 1:  softmax_body<64, 1, 32,  8192,  1024>(Spart, invnq, invnk, temperature, attnP, smem); break;
    case 2:  softmax_body<64, 2, 96,  40960, 5120>(Spart, invnq, invnk, temperature, attnP, smem); break;
    default: softmax_body<96, 3, 160, 73728, 9216>(Spart, invnq, invnk, temperature, attnP, smem); break;
  }
}

// ---------------- PV via 1-pass f16 MFMA, fused z epilogue -> single f16 ----------------
template<int G, int GI, int START, int AOFF>
__device__ void pv_body(
    const unsigned short* __restrict__ vTS, const unsigned short* __restrict__ attnP,
    const unsigned short* __restrict__ zqT,
    unsigned short* __restrict__ outT, unsigned short* __restrict__ zT,
    unsigned short* Ah, unsigned short* Bh)
{
  constexpr int NF = G / 16;
  const int t = threadIdx.x, b = blockIdx.y, l0 = blockIdx.x * 128;
  const int w = t >> 6, lane = t & 63, ln = lane & 15, lg = lane >> 4;
  const int lrow  = lane >> 2;
  const int chunk = (lane & 3) ^ ((lane >> 4) & 3);
  const int slot  = lg ^ (ln >> 2);
  f32x4 z4 = {0.f, 0.f, 0.f, 0.f};
  f32x4 acc[2][NF];
  #pragma unroll
  for (int i = 0; i < 2; i++)
    #pragma unroll
    for (int j = 0; j < NF; j++) acc[i][j] = z4;
  for (int kc = 0; kc < G; kc += 32) {
    #pragma unroll
    for (int i = 0; i < 2; i++) {
      const int rb = w * 32 + i * 16;
      const size_t g = ((size_t)b * L + l0 + rb + lrow) * 256 + START + kc + chunk * 8;
      gl16(vTS + g, &Ah[rb * 32]);
    }
    for (int i = w; i < G / 16; i += 4) {
      const int rb = i * 16;
      const size_t g = (size_t)b * 18432 + AOFF + (size_t)(rb + lrow) * G + kc + chunk * 8;
      gl16(attnP + g, &Bh[rb * 32]);
    }
    __syncthreads();
    short8v bhf[NF];
    #pragma unroll
    for (int nf = 0; nf < NF; nf++)
      bhf[nf] = *(const short8v*)&Bh[(nf * 16 + ln) * 32 + slot * 8];
    #pragma unroll
    for (int mi = 0; mi < 2; mi++) {
      const int aoff = ((w * 2 + mi) * 16 + ln) * 32 + slot * 8;
      const short8v ah = *(const short8v*)&Ah[aoff];
      #pragma unroll
      for (int nf = 0; nf < NF; nf++)
        acc[mi][nf] = __builtin_amdgcn_mfma_f32_16x16x32_f16(ah, bhf[nf], acc[mi][nf], 0, 0, 0);
    }
    __syncthreads();
  }
  #pragma unroll
  for (int mi = 0; mi < 2; mi++) {
    const int lbase = l0 + (w * 2 + mi) * 16 + lg * 4;
    #pragma unroll
    for (int nf = 0; nf < NF; nf++) {
      const int col = START + nf * 16 + ln;
      #pragma unroll
      for (int r = 0; r < 4; r++) {
        const size_t idx = ((size_t)b * L + lbase + r) * 256 + col;
        const float v = acc[mi][nf][r];
        outT[idx] = f16b(v);
        zT[idx]   = f16b(v + f16tof(zqT[idx]));
      }
    }
  }
}

__global__ __launch_bounds__(256) void pv_kernel(
    const unsigned short* __restrict__ vTS, const unsigned short* __restrict__ attnP,
    const unsigned short* __restrict__ zqT,
    unsigned short* __restrict__ outT, unsigned short* __restrict__ zT)
{
  __shared__ unsigned short Ah[128 * 32];
  __shared__ unsigned short Bh[96 * 32];
  switch (blockIdx.z) {
    case 0:  pv_body<32, 0, 0,   0   >(vTS, attnP, zqT, outT, zT, Ah, Bh); break;
    case 1:  pv_body<64, 1, 32,  1024>(vTS, attnP, zqT, outT, zT, Ah, Bh); break;
    case 2:  pv_body<64, 2, 96,  5120>(vTS, attnP, zqT, outT, zT, Ah, Bh); break;
    default: pv_body<96, 3, 160, 9216>(vTS, attnP, zqT, outT, zT, Ah, Bh); break;
  }
}

// ---------------- qv_cache ----------------
__global__ __launch_bounds__(256) void qv_kernel(const float* __restrict__ sumq,
    const float* __restrict__ sumk, const float* __restrict__ invnq,
    const float* __restrict__ invnk, float* __restrict__ out2)
{
  const int b = blockIdx.x >> 8, r = blockIdx.x & 255;
  float val = 0.f;
  {
    const int idx = b * 256 + 0 + (r & 31);
    val += fmaf(sumq[idx], invnq[idx], sumk[idx] * invnk[idx]);
  }
  {
    const int idx = b * 256 + 32 + (r & 63);
    val += fmaf(sumq[idx], invnq[idx], sumk[idx] * invnk[idx]);
  }
  {
    const int idx = b * 256 + 96 + (r & 63);
    val += fmaf(sumq[idx], invnq[idx], sumk[idx] * invnk[idx]);
  }
  if (r < 192) {
    const int rm = (r < 96) ? r : r - 96;
    const int idx = b * 256 + 160 + rm;
    val += fmaf(sumq[idx], invnq[idx], sumk[idx] * invnk[idx]);
  }
  val *= (1.0f / 4096.f) * 0.25f * 0.9f;
  const float4 o = {val, val, val, val};
  float4* dst = reinterpret_cast<float4*>(out2 + ((size_t)b * C + r) * L);
  for (int i = threadIdx.x; i < 1024; i += 256) dst[i] = o;
}

// ---------------- launch ----------------
extern "C" void kernel_launch(void* const* d_in, const int* in_sizes, int n_in,
                              void* d_out, int out_size, void* d_ws, size_t ws_size,
                              hipStream_t stream)
{
  const float* x           = (const float*)d_in[0];
  const float* temperature = (const float*)d_in[1];
  const float* w_qkv       = (const float*)d_in[2];
  const float* w_dw        = (const float*)d_in[3];
  const float* w_proj      = (const float*)d_in[4];
  const float* w_gate      = (const float*)d_in[5];
  const float* b_gate      = (const float*)d_in[6];
  const float* w_down      = (const float*)d_in[7];
  const float* b_down      = (const float*)d_in[8];
  const float* w_up        = (const float*)d_in[9];
  const float* b_up        = (const float*)d_in[10];

  if (ws_size < 202548224ULL) return;

  char* ws = (char*)d_ws;
  // Region A [0, 96M):
  float*          qkvQ    = (float*)(ws);                      // 32MB fp32 q (dead after conv)
  unsigned short* kvF     = (unsigned short*)(ws + 33554432);  // 32MB f16 k,v (dead after conv)
  unsigned short* vTS     = (unsigned short*)(ws);             // 16MB (after conv)
  unsigned short* zqT     = (unsigned short*)(ws + 16777216);  // 16MB
  float*          Spart   = (float*)(ws + 33554432);           // 4.72MB (after conv)
  unsigned short* attnP   = (unsigned short*)(ws + 38797312);  // 288KB
  // Region B [96M, 192M):
  unsigned short* XThi    = (unsigned short*)(ws + 100663296); // 16MB (dead after qkv)
  unsigned short* XTlo    = (unsigned short*)(ws + 117440512); // 16MB
  unsigned short* qkF     = (unsigned short*)(ws + 100663296); // 32MB (conv out)
  unsigned short* vF      = (unsigned short*)(ws + 134217728); // 16MB
  unsigned short* outT    = (unsigned short*)(ws + 150994944); // 16MB
  unsigned short* zT      = (unsigned short*)(ws + 167772160); // 16MB
  // Region C [192M+, persistent):
  unsigned short* Wf16   = (unsigned short*)(ws + 201326592);  // qkv/gate/down/up f16 + projH/projL
  unsigned short* WprojH = (unsigned short*)(ws + 201981952);  // = Wf16 + 327680
  unsigned short* WprojL = (unsigned short*)(ws + 202113024);  // = Wf16 + 393216
  float* csum   = (float*)(ws + 202244096);
  float* csumsq = (float*)(ws + 202260480);
  float* sumq   = (float*)(ws + 202276864);
  float* sumk   = (float*)(ws + 202285056);
  float* invnq  = (float*)(ws + 202293248);
  float* invnk  = (float*)(ws + 202301440);
  int*   order  = (int*)(ws + 202309632);

  float* out_all = (float*)d_out;
  float* qv_out  = out_all + (size_t)B * C * L;

  // 0. weight + input splits
  wsplit_kernel<<<1536, 256, 0, stream>>>(w_qkv, w_gate, w_down, w_up, w_proj,
                                          Wf16, WprojH, WprojL);
  splitx_kernel<<<dim3(64, 4, 8), 256, 0, stream>>>(x, XThi, XTlo);
  // 1. qkv: q-blocks 2-pass -> fp32; k/v-blocks 1-pass -> f16
  hgemm<256, 6, 2><<<dim3(32, 6, 8), 256, 0, stream>>>(
      XThi, XTlo, Wf16, qkvQ, kvF, 768);
  // 2. depthwise conv (q fp32-in, k/v f16-in) -> qkF/vF single f16 + stats
  dwconv2_kernel<<<dim3(768, 8), 256, 0, stream>>>(qkvQ, kvF, w_dw, qkF, vF, csum, csumsq);
  // 3. channel ordering + sorted stats
  rankstats_kernel<<<1, 256, 0, stream>>>(csum, csumsq, order, sumq, sumk, invnq, invnk);
  // 4. pack v^T sorted + zq (single f16)
  vpack_kernel<<<dim3(64, 8), 256, 0, stream>>>(vF, qkF, order, invnq, invnk, vTS, zqT);
  // 5. attention (1-pass f16)
  scores_kernel<<<dim3(8, 8, 5), 256, 0, stream>>>(qkF, order, Spart);
  softmax_kernel<<<dim3(8, 4, 4), 256, 9216, stream>>>(Spart, invnq, invnk, temperature, attnP);
  pv_kernel<<<dim3(32, 8, 4), 256, 0, stream>>>(vTS, attnP, zqT, outT, zT);
  // 6. FUSED gate+down+up+proj, 64-stage counted-vmcnt pipeline -> output 0
  mlp_fused_kernel<<<dim3(64, 8), 256, 0, stream>>>(
      zT, outT, Wf16, b_gate, b_down, b_up, out_all);
  // 7. qv_cache -> output 1
  qv_kernel<<<2048, 256, 0, stream>>>(sumq, sumk, invnq, invnk, qv_out);
}

// Round 14
// 206.736 us; speedup vs baseline: 1.6113x; 1.6113x over previous
//
#include <hip/hip_runtime.h>
#include <hip/hip_fp16.h>
#include <math.h>

#define B 8
#define C 256
#define L 4096
#define OC3 768

typedef __attribute__((ext_vector_type(8))) short short8v;
typedef __attribute__((ext_vector_type(8))) unsigned short u16x8;
typedef __attribute__((ext_vector_type(4))) float f32x4;

// ---------------- helpers ----------------
__device__ __forceinline__ float gelu_exact(float x){
  return 0.5f * x * (1.0f + erff(x * 0.70710678118654752440f));
}
__device__ __forceinline__ float wave_sum(float v){
  #pragma unroll
  for (int off = 32; off > 0; off >>= 1) v += __shfl_down(v, off, 64);
  return v;
}
__device__ __forceinline__ unsigned short f16b(float f){
  return __half_as_ushort(__float2half_rn(f));
}
__device__ __forceinline__ float f16tof(unsigned short u){
  return __half2float(__ushort_as_half(u));
}
__device__ __forceinline__ unsigned int splitpackh(float v){
  unsigned short hi = f16b(v);
  float lof = v - f16tof(hi);
  unsigned short lo = f16b(lof);
  return (unsigned int)hi | ((unsigned int)lo << 16);
}
// async global->LDS 16B per lane; LDS dest must be wave-uniform base
__device__ __forceinline__ void gl16(const unsigned short* g, unsigned short* l){
  __builtin_amdgcn_global_load_lds(
      (const __attribute__((address_space(1))) void*)g,
      (__attribute__((address_space(3))) void*)l, 16, 0, 0);
}

// ---------------- weight split ----------------
// Wf16: qkv@0 (196608), gate@196608 (65536), down@262144 (32768), up@294912 (32768) -- f16
// proj -> f16 hi/lo PAIR planes (65536 each)
__global__ __launch_bounds__(256) void wsplit_kernel(
    const float* __restrict__ wqkv, const float* __restrict__ wgate,
    const float* __restrict__ wdown, const float* __restrict__ wup,
    const float* __restrict__ wproj,
    unsigned short* __restrict__ Wf16,
    unsigned short* __restrict__ PH, unsigned short* __restrict__ PLo)
{
  int idx = blockIdx.x * 256 + threadIdx.x;   // 0..393215
  if (idx < 327680) {
    float s;
    if (idx < 196608)      s = wqkv[idx];
    else if (idx < 262144) s = wgate[idx - 196608];
    else if (idx < 294912) s = wdown[idx - 262144];
    else                   s = wup[idx - 294912];
    Wf16[idx] = f16b(s);
  } else {
    int j = idx - 327680;
    float wv = wproj[j];
    unsigned short hh = f16b(wv);
    PH[j]  = hh;
    PLo[j] = f16b(wv - f16tof(hh));
  }
}

// ---------------- x [b][c][l] fp32 -> xT hi/lo f16 [b][l][c] ----------------
__global__ __launch_bounds__(256) void splitx_kernel(const float* __restrict__ x,
    unsigned short* __restrict__ XThi, unsigned short* __restrict__ XTlo)
{
  __shared__ float st[64][68];
  const int b = blockIdx.z, c0 = blockIdx.y * 64, lb = blockIdx.x * 64;
  const int t = threadIdx.x;
  #pragma unroll
  for (int i = 0; i < 4; i++) {
    int row = (t >> 4) + i * 16;
    int col = (t & 15) * 4;
    float4 v = *(const float4*)&x[((size_t)b * C + c0 + row) * L + lb + col];
    st[row][col] = v.x; st[row][col+1] = v.y; st[row][col+2] = v.z; st[row][col+3] = v.w;
  }
  __syncthreads();
  const int l = t >> 2, cq = t & 3;
  u16x8 hv0, hv1, lv0, lv1;
  #pragma unroll
  for (int i = 0; i < 16; i++) {
    unsigned int p = splitpackh(st[cq * 16 + i][l]);
    if (i < 8) { hv0[i] = (unsigned short)(p & 0xFFFFu); lv0[i] = (unsigned short)(p >> 16); }
    else       { hv1[i-8] = (unsigned short)(p & 0xFFFFu); lv1[i-8] = (unsigned short)(p >> 16); }
  }
  size_t o = ((size_t)b * L + lb + l) * C + c0 + cq * 16;
  *(u16x8*)&XThi[o]     = hv0;
  *(u16x8*)&XThi[o + 8] = hv1;
  *(u16x8*)&XTlo[o]     = lv0;
  *(u16x8*)&XTlo[o + 8] = lv1;
}

// ---------------- f16 MFMA GEMM (qkv only), 2-phase double-buffered ----------------
template<int KTOT, int EPI, int MODE>
__global__ __launch_bounds__(256) void hgemm(
    const unsigned short* __restrict__ Ahi_g, const unsigned short* __restrict__ Alo_g,
    const unsigned short* __restrict__ Bw_g,
    float* __restrict__ outF,
    unsigned short* __restrict__ outH,
    int Ntot)
{
  __shared__ unsigned short SB[2][3][128 * 32];
  const int t  = threadIdx.x;
  const int lb = blockIdx.x * 128;
  const int o0 = blockIdx.y * 128;
  const int b  = blockIdx.z;
  const int w  = t >> 6, lane = t & 63;
  const int wm = w >> 1, wn = w & 1;
  const int ln = lane & 15, lg = lane >> 4;
  const int lrow  = lane >> 2;
  const int chunk = (lane & 3) ^ ((lane >> 4) & 3);
  const int slot  = lg ^ (ln >> 2);
  const bool twop = (blockIdx.y < 2);

  f32x4 z4 = {0.f, 0.f, 0.f, 0.f};
  f32x4 acc[4][4];
  #pragma unroll
  for (int i = 0; i < 4; i++)
    #pragma unroll
    for (int j = 0; j < 4; j++) acc[i][j] = z4;

  const size_t arow0 = (size_t)b * L + lb;
  constexpr int NKT = KTOT / 32;

  auto stage = [&](int kt, int cb) {
    const int k0 = kt * 32;
    #pragma unroll
    for (int i = 0; i < 2; i++) {
      const int rb = w * 32 + i * 16;
      const size_t ga = (arow0 + rb + lrow) * KTOT + k0 + chunk * 8;
      gl16(Ahi_g + ga, &SB[cb][0][rb * 32]);
      if (twop) gl16(Alo_g + ga, &SB[cb][1][rb * 32]);
      const size_t gb = (size_t)(o0 + rb + lrow) * KTOT + k0 + chunk * 8;
      gl16(Bw_g + gb, &SB[cb][2][rb * 32]);
    }
  };

  stage(0, 0);
  __syncthreads();
  int cur = 0;
  for (int kt = 0; kt < NKT; ++kt) {
    if (kt + 1 < NKT) stage(kt + 1, cur ^ 1);
    short8v bwf[4];
    #pragma unroll
    for (int nf = 0; nf < 4; nf++) {
      const int off = (wn * 64 + nf * 16 + ln) * 32 + slot * 8;
      bwf[nf] = *(const short8v*)&SB[cur][2][off];
    }
    #pragma unroll
    for (int mf = 0; mf < 4; mf++) {
      const int off = (wm * 64 + mf * 16 + ln) * 32 + slot * 8;
      const short8v ah = *(const short8v*)&SB[cur][0][off];
      #pragma unroll
      for (int nf = 0; nf < 4; nf++)
        acc[mf][nf] = __builtin_amdgcn_mfma_f32_16x16x32_f16(ah, bwf[nf], acc[mf][nf], 0, 0, 0);
      if (twop) {
        const short8v al = *(const short8v*)&SB[cur][1][off];
        #pragma unroll
        for (int nf = 0; nf < 4; nf++)
          acc[mf][nf] = __builtin_amdgcn_mfma_f32_16x16x32_f16(al, bwf[nf], acc[mf][nf], 0, 0, 0);
      }
    }
    __syncthreads();
    cur ^= 1;
  }
  #pragma unroll
  for (int mf = 0; mf < 4; mf++) {
    const int mbase = lb + wm * 64 + mf * 16 + lg * 4;
    #pragma unroll
    for (int nf = 0; nf < 4; nf++) {
      const int o = o0 + wn * 64 + nf * 16 + ln;
      if (o0 < 256) {
        float4 r;
        r.x = acc[mf][nf][0]; r.y = acc[mf][nf][1];
        r.z = acc[mf][nf][2]; r.w = acc[mf][nf][3];
        *(float4*)&outF[((size_t)b * 256 + o) * L + mbase] = r;
      } else {
        ushort4 r;
        r.x = f16b(acc[mf][nf][0]); r.y = f16b(acc[mf][nf][1]);
        r.z = f16b(acc[mf][nf][2]); r.w = f16b(acc[mf][nf][3]);
        *(ushort4*)&outH[((size_t)b * 512 + (o - 256)) * L + mbase] = r;
      }
    }
  }
}

// ---------------- FUSED MLP + PROJ v3: 64-row blocks, 80KB LDS, 2 blocks/CU ----------------
// Per block: 64 l-rows, batch b. Each wave owns rows [w*16, w*16+16) through the whole
// chain (zL & mL hazards are wave-local -> lockstep-safe, no epilogue barriers).
// 32 weight stages of [64][128] through wL[2] ping-pong (issue next, gemm cur, barrier).
__global__ __launch_bounds__(256, 2) void mlp_fused_kernel(
    const unsigned short* __restrict__ zT,     // [b][l][256] f16
    const unsigned short* __restrict__ outT,   // [b][l][256] f16
    const unsigned short* __restrict__ Wg,     // [256][256] f16
    const unsigned short* __restrict__ Wd,     // [128][256] f16
    const unsigned short* __restrict__ Wu,     // [256][128] f16
    const unsigned short* __restrict__ WpH,    // [256][256] f16 hi
    const unsigned short* __restrict__ WpL,    // [256][256] f16 lo
    const float* __restrict__ bg, const float* __restrict__ bd, const float* __restrict__ bu,
    float* __restrict__ out0)                  // [b][256][L] fp32
{
  __shared__ unsigned short zL[64 * 256];      // 32KB
  __shared__ unsigned short wL[2][64 * 128];   // 2 x 16KB
  __shared__ unsigned short mL[64 * 128];      // 16KB
  const int t = threadIdx.x;
  const int l0 = blockIdx.x * 64;
  const int b  = blockIdx.y;
  const int w = t >> 6, lane = t & 63;
  const int ln = lane & 15, lg = lane >> 4;

  // ---- z tile: wave-local rows, pre-swizzled source, linear gl16 dest ----
  {
    const int rIn = lane >> 5, ch = lane & 31;
    #pragma unroll
    for (int j = 0; j < 8; j++) {
      const int rowbase = w * 16 + j * 2;
      const int row = rowbase + rIn;
      const int sc = ch ^ (row & 7);
      gl16(zT + ((size_t)b * L + l0 + row) * 256 + sc * 8, &zL[rowbase * 256]);
    }
  }
  auto issueW = [&](int cb, const unsigned short* src, int rowstride) {
    const int rIn = lane >> 4, ch = lane & 15;
    #pragma unroll
    for (int j = 0; j < 4; j++) {
      const int rowbase = j * 16 + w * 4;
      const int row = rowbase + rIn;
      const int sc = ch ^ (row & 7);
      gl16(src + (size_t)row * rowstride + sc * 8, &wL[cb][rowbase * 128]);
    }
  };
  auto fragZ = [&](int row, int cc) -> short8v {
    return *(const short8v*)&zL[row * 256 + (cc ^ (row & 7)) * 8];
  };
  auto fragW = [&](int cb, int row, int cc) -> short8v {
    return *(const short8v*)&wL[cb][row * 128 + (cc ^ (row & 7)) * 8];
  };
  auto fragM = [&](int row, int cc) -> short8v {
    return *(const short8v*)&mL[row * 128 + (cc ^ (row & 7)) * 8];
  };
  // one stage gemm: 64l x 64o x K128, wave w owns rows [w*16, w*16+16)
  auto gemmZt = [&](f32x4 (&acc)[4], int buf, int cbase) {
    #pragma unroll
    for (int ks = 0; ks < 4; ks++) {
      const short8v af = fragZ(w * 16 + ln, cbase + ks * 4 + lg);
      #pragma unroll
      for (int nf = 0; nf < 4; nf++) {
        const short8v bf = fragW(buf, nf * 16 + ln, ks * 4 + lg);
        acc[nf] = __builtin_amdgcn_mfma_f32_16x16x32_f16(af, bf, acc[nf], 0, 0, 0);
      }
    }
  };
  auto gemmMt = [&](f32x4 (&acc)[4], int buf) {
    #pragma unroll
    for (int ks = 0; ks < 4; ks++) {
      const short8v af = fragM(w * 16 + ln, ks * 4 + lg);
      #pragma unroll
      for (int nf = 0; nf < 4; nf++) {
        const short8v bf = fragW(buf, nf * 16 + ln, ks * 4 + lg);
        acc[nf] = __builtin_amdgcn_mfma_f32_16x16x32_f16(af, bf, acc[nf], 0, 0, 0);
      }
    }
  };

  const f32x4 zz = {0.f, 0.f, 0.f, 0.f};
  issueW(0, Wg, 256);          // G(0,0)
  __syncthreads();

  // ---- gate: 8 stages ----
  f32x4 aG[4][4];
  #pragma unroll
  for (int i = 0; i < 4; i++)
    #pragma unroll
    for (int j = 0; j < 4; j++) aG[i][j] = zz;
  issueW(1, Wg + 128,           256); gemmZt(aG[0], 0, 0);  __syncthreads();
  issueW(0, Wg + 64*256,        256); gemmZt(aG[0], 1, 16); __syncthreads();
  issueW(1, Wg + 64*256 + 128,  256); gemmZt(aG[1], 0, 0);  __syncthreads();
  issueW(0, Wg + 128*256,       256); gemmZt(aG[1], 1, 16); __syncthreads();
  issueW(1, Wg + 128*256 + 128, 256); gemmZt(aG[2], 0, 0);  __syncthreads();
  issueW(0, Wg + 192*256,       256); gemmZt(aG[2], 1, 16); __syncthreads();
  issueW(1, Wg + 192*256 + 128, 256); gemmZt(aG[3], 0, 0);  __syncthreads();
  issueW(0, Wd,                 256); gemmZt(aG[3], 1, 16); __syncthreads();
  // gate epilogue (wave-local rows; lockstep-safe, no barrier)
  #pragma unroll
  for (int oc = 0; oc < 4; oc++)
    #pragma unroll
    for (int nf = 0; nf < 4; nf++)
      #pragma unroll
      for (int r = 0; r < 4; r++) {
        const int l = w * 16 + lg * 4 + r;
        const int o = oc * 64 + nf * 16 + ln;
        const int a = l * 256 + (((o >> 3) ^ (l & 7)) << 3) + (o & 7);
        zL[a] = f16b(gelu_exact(aG[oc][nf][r] + bg[o]) * f16tof(zL[a]));
      }
  // ---- down: 4 stages ----
  f32x4 aD[2][4];
  #pragma unroll
  for (int i = 0; i < 2; i++)
    #pragma unroll
    for (int j = 0; j < 4; j++) aD[i][j] = zz;
  issueW(1, Wd + 128,           256); gemmZt(aD[0], 0, 0);  __syncthreads();
  issueW(0, Wd + 64*256,        256); gemmZt(aD[0], 1, 16); __syncthreads();
  issueW(1, Wd + 64*256 + 128,  256); gemmZt(aD[1], 0, 0);  __syncthreads();
  issueW(0, Wu,                 128); gemmZt(aD[1], 1, 16); __syncthreads();
  // down epilogue -> mL (wave-local)
  #pragma unroll
  for (int oc = 0; oc < 2; oc++)
    #pragma unroll
    for (int nf = 0; nf < 4; nf++)
      #pragma unroll
      for (int r = 0; r < 4; r++) {
        const int l = w * 16 + lg * 4 + r;
        const int o = oc * 64 + nf * 16 + ln;
        mL[l * 128 + (((o >> 3) ^ (l & 7)) << 3) + (o & 7)] = f16b(aD[oc][nf][r] + bd[o]);
      }
  // ---- up: 4 stages ----
  f32x4 aU[4][4];
  #pragma unroll
  for (int i = 0; i < 4; i++)
    #pragma unroll
    for (int j = 0; j < 4; j++) aU[i][j] = zz;
  issueW(1, Wu + 64*128,        128); gemmMt(aU[0], 0); __syncthreads();
  issueW(0, Wu + 128*128,       128); gemmMt(aU[1], 1); __syncthreads();
  issueW(1, Wu + 192*128,       128); gemmMt(aU[2], 0); __syncthreads();
  issueW(0, WpH,                256); gemmMt(aU[3], 1); __syncthreads();
  // up epilogue: preproj = aU + bu + outT, overwrite zL (wave-local)
  #pragma unroll
  for (int oc = 0; oc < 4; oc++)
    #pragma unroll
    for (int nf = 0; nf < 4; nf++)
      #pragma unroll
      for (int r = 0; r < 4; r++) {
        const int l = w * 16 + lg * 4 + r;
        const int o = oc * 64 + nf * 16 + ln;
        const float v = aU[oc][nf][r] + bu[o]
                      + f16tof(outT[((size_t)b * L + l0 + l) * 256 + o]);
        zL[l * 256 + (((o >> 3) ^ (l & 7)) << 3) + (o & 7)] = f16b(v);
      }
  // ---- proj: 16 stages (2-pass f16-pair weights) ----
  f32x4 aP[4][4];
  #pragma unroll
  for (int i = 0; i < 4; i++)
    #pragma unroll
    for (int j = 0; j < 4; j++) aP[i][j] = zz;
  issueW(1, WpL,                256); gemmZt(aP[0], 0, 0);  __syncthreads();
  issueW(0, WpH + 128,          256); gemmZt(aP[0], 1, 0);  __syncthreads();
  issueW(1, WpL + 128,          256); gemmZt(aP[0], 0, 16); __syncthreads();
  issueW(0, WpH + 64*256,       256); gemmZt(aP[0], 1, 16); __syncthreads();
  issueW(1, WpL + 64*256,       256); gemmZt(aP[1], 0, 0);  __syncthreads();
  issueW(0, WpH + 64*256 + 128, 256); gemmZt(aP[1], 1, 0);  __syncthreads();
  issueW(1, WpL + 64*256 + 128, 256); gemmZt(aP[1], 0, 16); __syncthreads();
  issueW(0, WpH + 128*256,      256); gemmZt(aP[1], 1, 16); __syncthreads();
  issueW(1, WpL + 128*256,      256); gemmZt(aP[2], 0, 0);  __syncthreads();
  issueW(0, WpH + 128*256 + 128,256); gemmZt(aP[2], 1, 0);  __syncthreads();
  issueW(1, WpL + 128*256 + 128,256); gemmZt(aP[2], 0, 16); __syncthreads();
  issueW(0, WpH + 192*256,      256); gemmZt(aP[2], 1, 16); __syncthreads();
  issueW(1, WpL + 192*256,      256); gemmZt(aP[3], 0, 0);  __syncthreads();
  issueW(0, WpH + 192*256 + 128,256); gemmZt(aP[3], 1, 0);  __syncthreads();
  issueW(1, WpL + 192*256 + 128,256); gemmZt(aP[3], 0, 16); __syncthreads();
                                      gemmZt(aP[3], 1, 16);
  // proj write
  #pragma unroll
  for (int oc = 0; oc < 4; oc++)
    #pragma unroll
    for (int nf = 0; nf < 4; nf++) {
      const int o = oc * 64 + nf * 16 + ln;
      float4 r4;
      r4.x = aP[oc][nf][0]; r4.y = aP[oc][nf][1];
      r4.z = aP[oc][nf][2]; r4.w = aP[oc][nf][3];
      *(float4*)&out0[((size_t)b * 256 + o) * L + l0 + w * 16 + lg * 4] = r4;
    }
}

// ---------------- depthwise 3x3 conv: q from fp32, k/v from f16; out single f16 ----------------
__global__ __launch_bounds__(256) void dwconv2_kernel(
    const float* __restrict__ inQ, const unsigned short* __restrict__ inKV,
    const float* __restrict__ wdw,
    unsigned short* __restrict__ qkF, unsigned short* __restrict__ vF,
    float* __restrict__ csum, float* __restrict__ csumsq)
{
  __shared__ float p[66][73];
  __shared__ float rs[4][2];
  const int ch = blockIdx.x;
  const int b  = blockIdx.y;
  const int t  = threadIdx.x;
  float wt[9];
  #pragma unroll
  for (int j = 0; j < 9; j++) wt[j] = wdw[ch * 9 + j];
  if (t < 66) { p[0][3 + t] = 0.f; p[65][3 + t] = 0.f; }
  if (t < 64) { p[1 + t][3] = 0.f; p[1 + t][68] = 0.f; }
  if (ch < 256) {
    const size_t base = ((size_t)b * 256 + ch) * L;
    #pragma unroll
    for (int i = 0; i < 4; i++) {
      int pix = (i * 256 + t) * 4;
      const float4 v = *reinterpret_cast<const float4*>(&inQ[base + pix]);
      int h = pix >> 6, ww = pix & 63;
      p[1+h][4+ww] = v.x; p[1+h][5+ww] = v.y; p[1+h][6+ww] = v.z; p[1+h][7+ww] = v.w;
    }
  } else {
    const size_t base = ((size_t)b * 512 + (ch - 256)) * L + t * 16;
    const u16x8 a0 = *(const u16x8*)&inKV[base];
    const u16x8 a1 = *(const u16x8*)&inKV[base + 8];
    const int h = t >> 2, w0 = (t & 3) * 16;
    #pragma unroll
    for (int j = 0; j < 8; j++) {
      p[1+h][4+w0+j]   = f16tof((unsigned short)a0[j]);
      p[1+h][12+w0+j]  = f16tof((unsigned short)a1[j]);
    }
  }
  __syncthreads();
  const int h  = t >> 2;
  const int w0 = (t & 3) * 16;
  float r0a[18], r1a[18], r2a[18];
  #pragma unroll
  for (int c = 0; c < 18; c++) {
    r0a[c] = p[h][w0 + 3 + c];
    r1a[c] = p[h + 1][w0 + 3 + c];
    r2a[c] = p[h + 2][w0 + 3 + c];
  }
  float res[16];
  float s = 0.f, s2 = 0.f;
  #pragma unroll
  for (int j = 0; j < 16; j++) {
    float acc;
    acc = r0a[j] * wt[0];
    acc = fmaf(r0a[j+1], wt[1], acc);
    acc = fmaf(r0a[j+2], wt[2], acc);
    acc = fmaf(r1a[j],   wt[3], acc);
    acc = fmaf(r1a[j+1], wt[4], acc);
    acc = fmaf(r1a[j+2], wt[5], acc);
    acc = fmaf(r2a[j],   wt[6], acc);
    acc = fmaf(r2a[j+1], wt[7], acc);
    acc = fmaf(r2a[j+2], wt[8], acc);
    res[j] = acc;
    s += acc;
    s2 = fmaf(acc, acc, s2);
  }
  u16x8 h0v, h1v;
  #pragma unroll
  for (int j = 0; j < 16; j++) {
    if (j < 8) h0v[j]   = f16b(res[j]);
    else       h1v[j-8] = f16b(res[j]);
  }
  if (ch < 512) {
    const size_t qi = ((size_t)b * 512 + ch) * L + t * 16;
    *(u16x8*)&qkF[qi]     = h0v;
    *(u16x8*)&qkF[qi + 8] = h1v;
    s = wave_sum(s); s2 = wave_sum(s2);
    const int lane = t & 63, wid = t >> 6;
    if (lane == 0) { rs[wid][0] = s; rs[wid][1] = s2; }
    __syncthreads();
    if (t == 0) {
      csum[b * 512 + ch]   = rs[0][0] + rs[1][0] + rs[2][0] + rs[3][0];
      csumsq[b * 512 + ch] = rs[0][1] + rs[1][1] + rs[2][1] + rs[3][1];
    }
  } else {
    const size_t vi = ((size_t)b * 256 + (ch - 512)) * L + t * 16;
    *(u16x8*)&vF[vi]     = h0v;
    *(u16x8*)&vF[vi + 8] = h1v;
  }
}

// ---------------- rank (stable descending) + sorted stats ----------------
__global__ __launch_bounds__(256) void rankstats_kernel(
    const float* __restrict__ csum, const float* __restrict__ csumsq,
    int* __restrict__ order,
    float* __restrict__ sumq, float* __restrict__ sumk,
    float* __restrict__ invnq, float* __restrict__ invnk)
{
  const int c = threadIdx.x;
  float key = 0.f;
  #pragma unroll
  for (int b = 0; b < 8; b++) key += csum[b * 512 + c];
  __shared__ float keys[256];
  __shared__ int ordS[256];
  keys[c] = key;
  __syncthreads();
  int rank = 0;
  for (int j = 0; j < 256; j++) {
    float kj = keys[j];
    rank += (kj > key) || (kj == key && j < c);
  }
  order[rank] = c;
  ordS[rank] = c;
  __syncthreads();
  const int ch = ordS[c];
  #pragma unroll
  for (int b = 0; b < 8; b++) {
    sumq[b * 256 + c]  = csum[b * 512 + ch];
    invnq[b * 256 + c] = 1.0f / fmaxf(sqrtf(csumsq[b * 512 + ch]), 1e-12f);
    sumk[b * 256 + c]  = csum[b * 512 + 256 + ch];
    invnk[b * 256 + c] = 1.0f / fmaxf(sqrtf(csumsq[b * 512 + 256 + ch]), 1e-12f);
  }
}

// ---------------- pack: vTS = v^T sorted (f16) [b][l][r]; zqT = qn+kn (f16) [b][l][r] ----------------
__global__ __launch_bounds__(256) void vpack_kernel(
    const unsigned short* __restrict__ vF, const unsigned short* __restrict__ qkF,
    const int* __restrict__ order,
    const float* __restrict__ invnq, const float* __restrict__ invnk,
    unsigned short* __restrict__ vTS, unsigned short* __restrict__ zqT)
{
  __shared__ float vt[64][65];
  __shared__ float zt[64][65];
  __shared__ int   ordS[256];
  __shared__ float iqS[256], ikS[256];
  const int t = threadIdx.x, lb = blockIdx.x * 64, b = blockIdx.y;
  ordS[t] = order[t];
  iqS[t] = invnq[b * 256 + t];
  ikS[t] = invnk[b * 256 + t];
  __syncthreads();
  for (int cc = 0; cc < 4; cc++) {
    const int r0 = cc * 64;
    for (int i = t; i < 1024; i += 256) {
      const int row = i >> 4, q = i & 15;
      const int ch = ordS[r0 + row];
      const float iq = iqS[r0 + row], ik = ikS[r0 + row];
      const ushort4 v4 = *(const ushort4*)&vF[((size_t)b * 256 + ch) * L + lb + q * 4];
      vt[q*4+0][row] = f16tof(v4.x); vt[q*4+1][row] = f16tof(v4.y);
      vt[q*4+2][row] = f16tof(v4.z); vt[q*4+3][row] = f16tof(v4.w);
      const ushort4 q4 = *(const ushort4*)&qkF[((size_t)b * 512 + ch) * L + lb + q * 4];
      const ushort4 k4 = *(const ushort4*)&qkF[((size_t)b * 512 + 256 + ch) * L + lb + q * 4];
      zt[q*4+0][row] = f16tof(q4.x) * iq + f16tof(k4.x) * ik;
      zt[q*4+1][row] = f16tof(q4.y) * iq + f16tof(k4.y) * ik;
      zt[q*4+2][row] = f16tof(q4.z) * iq + f16tof(k4.z) * ik;
      zt[q*4+3][row] = f16tof(q4.w) * iq + f16tof(k4.w) * ik;
    }
    __syncthreads();
    const int l = t >> 2, qq = t & 3;
    const size_t ob = ((size_t)b * L + lb + l) * 256 + r0 + qq * 16;
    u16x8 vv[2], zz[2];
    #pragma unroll
    for (int j = 0; j < 16; j++) {
      vv[j>>3][j&7] = f16b(vt[l][qq*16 + j]);
      zz[j>>3][j&7] = f16b(zt[l][qq*16 + j]);
    }
    *(u16x8*)&vTS[ob]     = vv[0]; *(u16x8*)&vTS[ob + 8] = vv[1];
    *(u16x8*)&zqT[ob]     = zz[0]; *(u16x8*)&zqT[ob + 8] = zz[1];
    __syncthreads();
  }
}

// ---------------- scores via 1-pass f16 MFMA, 2-phase gather staging ----------------
template<int G, int GI, int START, int MB, int SPB>
__device__ void scores_body(const unsigned short* __restrict__ qkF,
    const int* __restrict__ order, float* __restrict__ Spart,
    unsigned short* Ah, unsigned short* Bh, int* ordS)
{
  constexpr int MR = (G - MB * 64 < 64) ? (G - MB * 64) : 64;
  constexpr int NF = G / 16;
  const int t = threadIdx.x, ks = blockIdx.x, b = blockIdx.y;
  const int w = t >> 6, lane = t & 63, ln = lane & 15, lg = lane >> 4;
  const int lrow  = lane >> 2;
  const int chunk = (lane & 3) ^ ((lane >> 4) & 3);
  const int slot  = lg ^ (ln >> 2);
  for (int i = t; i < G; i += 256) ordS[i] = order[START + i];
  __syncthreads();
  const int k0 = ks * 512;
  const bool act = (w * 16) < MR;
  f32x4 z4 = {0.f, 0.f, 0.f, 0.f};
  f32x4 acc[NF];
  #pragma unroll
  for (int i = 0; i < NF; i++) acc[i] = z4;

  auto stage = [&](int kc, int cb) {
    for (int i = w; i < MR / 16; i += 4) {
      const int rb = i * 16;
      const int ch = ordS[MB * 64 + rb + lrow];
      const size_t g = ((size_t)b * 512 + ch) * L + k0 + kc + chunk * 8;
      gl16(qkF + g, &Ah[cb * 2048 + rb * 32]);
    }
    for (int i = w; i < G / 16; i += 4) {
      const int rb = i * 16;
      const int ch = 256 + ordS[rb + lrow];
      const size_t g = ((size_t)b * 512 + ch) * L + k0 + kc + chunk * 8;
      gl16(qkF + g, &Bh[cb * 3072 + rb * 32]);
    }
  };

  stage(0, 0);
  __syncthreads();
  int cur = 0;
  for (int kc = 0; kc < 512; kc += 32) {
    if (kc + 32 < 512) stage(kc + 32, cur ^ 1);
    if (act) {
      const int aoff = cur * 2048 + (w * 16 + ln) * 32 + slot * 8;
      const short8v ah = *(const short8v*)&Ah[aoff];
      #pragma unroll
      for (int nf = 0; nf < NF; nf++) {
        const int boff = cur * 3072 + (nf * 16 + ln) * 32 + slot * 8;
        const short8v bh = *(const short8v*)&Bh[boff];
        acc[nf] = __builtin_amdgcn_mfma_f32_16x16x32_f16(ah, bh, acc[nf], 0, 0, 0);
      }
    }
    __syncthreads();
    cur ^= 1;
  }
  if (act) {
    float* dst = Spart + (size_t)b * 147456 + SPB + ks * G * G;
    #pragma unroll
    for (int nf = 0; nf < NF; nf++) {
      const int d = nf * 16 + ln;
      #pragma unroll
      for (int r = 0; r < 4; r++) {
        const int m = MB * 64 + w * 16 + lg * 4 + r;
        dst[m * G + d] = acc[nf][r];
      }
    }
  }
}

__global__ __launch_bounds__(256) void scores_kernel(const unsigned short* __restrict__ qkF,
    const int* __restrict__ order, float* __restrict__ Spart)
{
  __shared__ unsigned short Ah[2 * 64 * 32];
  __shared__ unsigned short Bh[2 * 96 * 32];
  __shared__ int ordS[96];
  switch (blockIdx.z) {
    case 0:  scores_body<32, 0, 0,   0, 0    >(qkF, order, Spart, Ah, Bh, ordS); break;
    case 1:  scores_body<64, 1, 32,  0, 8192 >(qkF, order, Spart, Ah, Bh, ordS); break;
    case 2:  scores_body<64, 2, 96,  0, 40960>(qkF, order, Spart, Ah, Bh, ordS); break;
    case 3:  scores_body<96, 3, 160, 0, 73728>(qkF, order, Spart, Ah, Bh, ordS); break;
    default: scores_body<96, 3, 160, 1, 73728>(qkF, order, Spart, Ah, Bh, ordS); break;
  }
}

// ---------------- reduce partials, scale, wave-parallel softmax -> single f16 attn ----------------
template<int G, int GI, int START, int SPB, int AOFF>
__device__ void softmax_body(const float* __restrict__ Spart, const float* __restrict__ invnq,
    const float* __restrict__ invnk, const float* __restrict__ temperature,
    unsigned short* __restrict__ attnP, float* Sm)
{
  constexpr int RQ = G / 4;
  const int t = threadIdx.x;
  const int b = blockIdx.x;
  const int r0 = blockIdx.z * RQ;
  const float temp = temperature[GI];
  for (int idx = t; idx < RQ * G; idx += 256) {
    const int rl = idx / G, d = idx - rl * G;
    const int gidx = (r0 + rl) * G + d;
    float s = 0.f;
    #pragma unroll
    for (int ks = 0; ks < 8; ks++)
      s += Spart[(size_t)b * 147456 + SPB + ks * G * G + gidx];
    Sm[idx] = s * invnq[b * 256 + START + r0 + rl] * invnk[b * 256 + START + d] * temp;
  }
  __syncthreads();
  const int wv = t >> 6, lane = t & 63;
  for (int r = wv; r < RQ; r += 4) {
    const float v0 = (lane < G) ? Sm[r * G + lane] : -INFINITY;
    const float v1 = (64 + lane < G) ? Sm[r * G + 64 + lane] : -INFINITY;
    float m = fmaxf(v0, v1);
    #pragma unroll
    for (int off = 32; off > 0; off >>= 1) m = fmaxf(m, __shfl_xor(m, off, 64));
    const float e0 = (lane < G) ? expf(v0 - m) : 0.f;
    const float e1 = (64 + lane < G) ? expf(v1 - m) : 0.f;
    float s = e0 + e1;
    #pragma unroll
    for (int off = 32; off > 0; off >>= 1) s += __shfl_xor(s, off, 64);
    const float inv = 1.0f / s;
    const size_t base = (size_t)b * 18432 + AOFF + (size_t)(r0 + r) * G;
    if (lane < G)      attnP[base + lane]      = f16b(e0 * inv);
    if (64 + lane < G) attnP[base + 64 + lane] = f16b(e1 * inv);
  }
}

__global__ __launch_bounds__(256) void softmax_kernel(const float* __restrict__ Spart,
    const float* __restrict__ invnq, const float* __restrict__ invnk,
    const float* __restrict__ temperature, unsigned short* __restrict__ attnP)
{
  extern __shared__ float smem[];
  switch (blockIdx.y) {
    case 0:  softmax_body<32, 0, 0,   0,     0   >(Spart, invnq, invnk, temperature, attnP, smem); break;
    case 1:  softmax_body<64, 1, 32,  8192,  1024>(Spart, invnq, invnk, temperature, attnP, smem); break;
    case 2:  softmax_body<64, 2, 96,  40960, 5120>(Spart, invnq, invnk, temperature, attnP, smem); break;
    default: softmax_body<96, 3, 160, 73728, 9216>(Spart, invnq, invnk, temperature, attnP, smem); break;
  }
}

// ---------------- PV via 1-pass f16 MFMA, fused z epilogue -> single f16 ----------------
template<int G, int GI, int START, int AOFF>
__device__ void pv_body(
    const unsigned short* __restrict__ vTS, const unsigned short* __restrict__ attnP,
    const unsigned short* __restrict__ zqT,
    unsigned short* __restrict__ outT, unsigned short* __restrict__ zT,
    unsigned short* Ah, unsigned short* Bh)
{
  constexpr int NF = G / 16;
  const int t = threadIdx.x, b = blockIdx.y, l0 = blockIdx.x * 128;
  const int w = t >> 6, lane = t & 63, ln = lane & 15, lg = lane >> 4;
  const int lrow  = lane >> 2;
  const int chunk = (lane & 3) ^ ((lane >> 4) & 3);
  const int slot  = lg ^ (ln >> 2);
  f32x4 z4 = {0.f, 0.f, 0.f, 0.f};
  f32x4 acc[2][NF];
  #pragma unroll
  for (int i = 0; i < 2; i++)
    #pragma unroll
    for (int j = 0; j < NF; j++) acc[i][j] = z4;
  for (int kc = 0; kc < G; kc += 32) {
    #pragma unroll
    for (int i = 0; i < 2; i++) {
      const int rb = w * 32 + i * 16;
      const size_t g = ((size_t)b * L + l0 + rb + lrow) * 256 + START + kc + chunk * 8;
      gl16(vTS + g, &Ah[rb * 32]);
    }
    for (int i = w; i < G / 16; i += 4) {
      const int rb = i * 16;
      const size_t g = (size_t)b * 18432 + AOFF + (size_t)(rb + lrow) * G + kc + chunk * 8;
      gl16(attnP + g, &Bh[rb * 32]);
    }
    __syncthreads();
    short8v bhf[NF];
    #pragma unroll
    for (int nf = 0; nf < NF; nf++)
      bhf[nf] = *(const short8v*)&Bh[(nf * 16 + ln) * 32 + slot * 8];
    #pragma unroll
    for (int mi = 0; mi < 2; mi++) {
      const int aoff = ((w * 2 + mi) * 16 + ln) * 32 + slot * 8;
      const short8v ah = *(const short8v*)&Ah[aoff];
      #pragma unroll
      for (int nf = 0; nf < NF; nf++)
        acc[mi][nf] = __builtin_amdgcn_mfma_f32_16x16x32_f16(ah, bhf[nf], acc[mi][nf], 0, 0, 0);
    }
    __syncthreads();
  }
  #pragma unroll
  for (int mi = 0; mi < 2; mi++) {
    const int lbase = l0 + (w * 2 + mi) * 16 + lg * 4;
    #pragma unroll
    for (int nf = 0; nf < NF; nf++) {
      const int col = START + nf * 16 + ln;
      #pragma unroll
      for (int r = 0; r < 4; r++) {
        const size_t idx = ((size_t)b * L + lbase + r) * 256 + col;
        const float v = acc[mi][nf][r];
        outT[idx] = f16b(v);
        zT[idx]   = f16b(v + f16tof(zqT[idx]));
      }
    }
  }
}

__global__ __launch_bounds__(256) void pv_kernel(
    const unsigned short* __restrict__ vTS, const unsigned short* __restrict__ attnP,
    const unsigned short* __restrict__ zqT,
    unsigned short* __restrict__ outT, unsigned short* __restrict__ zT)
{
  __shared__ unsigned short Ah[128 * 32];
  __shared__ unsigned short Bh[96 * 32];
  switch (blockIdx.z) {
    case 0:  pv_body<32, 0, 0,   0   >(vTS, attnP, zqT, outT, zT, Ah, Bh); break;
    case 1:  pv_body<64, 1, 32,  1024>(vTS, attnP, zqT, outT, zT, Ah, Bh); break;
    case 2:  pv_body<64, 2, 96,  5120>(vTS, attnP, zqT, outT, zT, Ah, Bh); break;
    default: pv_body<96, 3, 160, 9216>(vTS, attnP, zqT, outT, zT, Ah, Bh); break;
  }
}

// ---------------- qv_cache ----------------
__global__ __launch_bounds__(256) void qv_kernel(const float* __restrict__ sumq,
    const float* __restrict__ sumk, const float* __restrict__ invnq,
    const float* __restrict__ invnk, float* __restrict__ out2)
{
  const int b = blockIdx.x >> 8, r = blockIdx.x & 255;
  float val = 0.f;
  {
    const int idx = b * 256 + 0 + (r & 31);
    val += fmaf(sumq[idx], invnq[idx], sumk[idx] * invnk[idx]);
  }
  {
    const int idx = b * 256 + 32 + (r & 63);
    val += fmaf(sumq[idx], invnq[idx], sumk[idx] * invnk[idx]);
  }
  {
    const int idx = b * 256 + 96 + (r & 63);
    val += fmaf(sumq[idx], invnq[idx], sumk[idx] * invnk[idx]);
  }
  if (r < 192) {
    const int rm = (r < 96) ? r : r - 96;
    const int idx = b * 256 + 160 + rm;
    val += fmaf(sumq[idx], invnq[idx], sumk[idx] * invnk[idx]);
  }
  val *= (1.0f / 4096.f) * 0.25f * 0.9f;
  const float4 o = {val, val, val, val};
  float4* dst = reinterpret_cast<float4*>(out2 + ((size_t)b * C + r) * L);
  for (int i = threadIdx.x; i < 1024; i += 256) dst[i] = o;
}

// ---------------- launch ----------------
extern "C" void kernel_launch(void* const* d_in, const int* in_sizes, int n_in,
                              void* d_out, int out_size, void* d_ws, size_t ws_size,
                              hipStream_t stream)
{
  const float* x           = (const float*)d_in[0];
  const float* temperature = (const float*)d_in[1];
  const float* w_qkv       = (const float*)d_in[2];
  const float* w_dw        = (const float*)d_in[3];
  const float* w_proj      = (const float*)d_in[4];
  const float* w_gate      = (const float*)d_in[5];
  const float* b_gate      = (const float*)d_in[6];
  const float* w_down      = (const float*)d_in[7];
  const float* b_down      = (const float*)d_in[8];
  const float* w_up        = (const float*)d_in[9];
  const float* b_up        = (const float*)d_in[10];

  if (ws_size < 202548224ULL) return;

  char* ws = (char*)d_ws;
  // Region A [0, 96M):
  float*          qkvQ    = (float*)(ws);                      // 32MB fp32 q (dead after conv)
  unsigned short* kvF     = (unsigned short*)(ws + 33554432);  // 32MB f16 k,v (dead after conv)
  unsigned short* vTS     = (unsigned short*)(ws);             // 16MB (after conv)
  unsigned short* zqT     = (unsigned short*)(ws + 16777216);  // 16MB
  float*          Spart   = (float*)(ws + 33554432);           // 4.72MB (after conv)
  unsigned short* attnP   = (unsigned short*)(ws + 38797312);  // 288KB
  // Region B [96M, 192M):
  unsigned short* XThi    = (unsigned short*)(ws + 100663296); // 16MB (dead after qkv)
  unsigned short* XTlo    = (unsigned short*)(ws + 117440512); // 16MB
  unsigned short* qkF     = (unsigned short*)(ws + 100663296); // 32MB (conv out)
  unsigned short* vF      = (unsigned short*)(ws + 134217728); // 16MB
  unsigned short* outT    = (unsigned short*)(ws + 150994944); // 16MB
  unsigned short* zT      = (unsigned short*)(ws + 167772160); // 16MB
  // Region C [192M+, persistent):
  unsigned short* Wf16   = (unsigned short*)(ws + 201326592);  // 655360B
  unsigned short* WprojH = (unsigned short*)(ws + 201981952);  // 128KB
  unsigned short* WprojL = (unsigned short*)(ws + 202113024);  // 128KB
  float* csum   = (float*)(ws + 202244096);
  float* csumsq = (float*)(ws + 202260480);
  float* sumq   = (float*)(ws + 202276864);
  float* sumk   = (float*)(ws + 202285056);
  float* invnq  = (float*)(ws + 202293248);
  float* invnk  = (float*)(ws + 202301440);
  int*   order  = (int*)(ws + 202309632);

  float* out_all = (float*)d_out;
  float* qv_out  = out_all + (size_t)B * C * L;

  // 0. weight + input splits
  wsplit_kernel<<<1536, 256, 0, stream>>>(w_qkv, w_gate, w_down, w_up, w_proj,
                                          Wf16, WprojH, WprojL);
  splitx_kernel<<<dim3(64, 4, 8), 256, 0, stream>>>(x, XThi, XTlo);
  // 1. qkv: q-blocks 2-pass -> fp32; k/v-blocks 1-pass -> f16
  hgemm<256, 6, 2><<<dim3(32, 6, 8), 256, 0, stream>>>(
      XThi, XTlo, Wf16, qkvQ, kvF, 768);
  // 2. depthwise conv (q fp32-in, k/v f16-in) -> qkF/vF single f16 + stats
  dwconv2_kernel<<<dim3(768, 8), 256, 0, stream>>>(qkvQ, kvF, w_dw, qkF, vF, csum, csumsq);
  // 3. channel ordering + sorted stats
  rankstats_kernel<<<1, 256, 0, stream>>>(csum, csumsq, order, sumq, sumk, invnq, invnk);
  // 4. pack v^T sorted + zq (single f16)
  vpack_kernel<<<dim3(64, 8), 256, 0, stream>>>(vF, qkF, order, invnq, invnk, vTS, zqT);
  // 5. attention (1-pass f16)
  scores_kernel<<<dim3(8, 8, 5), 256, 0, stream>>>(qkF, order, Spart);
  softmax_kernel<<<dim3(8, 4, 4), 256, 9216, stream>>>(Spart, invnq, invnk, temperature, attnP);
  pv_kernel<<<dim3(32, 8, 4), 256, 0, stream>>>(vTS, attnP, zqT, outT, zT);
  // 6. FUSED gate+down+up+proj (64-row blocks, 2 blocks/CU) -> output 0
  mlp_fused_kernel<<<dim3(64, 8), 256, 0, stream>>>(
      zT, outT, Wf16 + 196608, Wf16 + 262144, Wf16 + 294912, WprojH, WprojL,
      b_gate, b_down, b_up, out_all);
  // 7. qv_cache -> output 1
  qv_kernel<<<2048, 256, 0, stream>>>(sumq, sumk, invnq, invnk, qv_out);
}

// Round 15
// 201.712 us; speedup vs baseline: 1.6515x; 1.0249x over previous
//
#include <hip/hip_runtime.h>
#include <hip/hip_fp16.h>
#include <math.h>

#define B 8
#define C 256
#define L 4096
#define OC3 768

typedef __attribute__((ext_vector_type(8))) short short8v;
typedef __attribute__((ext_vector_type(8))) unsigned short u16x8;
typedef __attribute__((ext_vector_type(4))) float f32x4;

// ---------------- helpers ----------------
__device__ __forceinline__ float gelu_exact(float x){
  return 0.5f * x * (1.0f + erff(x * 0.70710678118654752440f));
}
__device__ __forceinline__ float wave_sum(float v){
  #pragma unroll
  for (int off = 32; off > 0; off >>= 1) v += __shfl_down(v, off, 64);
  return v;
}
__device__ __forceinline__ unsigned short f16b(float f){
  return __half_as_ushort(__float2half_rn(f));
}
__device__ __forceinline__ float f16tof(unsigned short u){
  return __half2float(__ushort_as_half(u));
}
__device__ __forceinline__ unsigned int splitpackh(float v){
  unsigned short hi = f16b(v);
  float lof = v - f16tof(hi);
  unsigned short lo = f16b(lof);
  return (unsigned int)hi | ((unsigned int)lo << 16);
}
// async global->LDS 16B per lane; LDS dest must be wave-uniform base
__device__ __forceinline__ void gl16(const unsigned short* g, unsigned short* l){
  __builtin_amdgcn_global_load_lds(
      (const __attribute__((address_space(1))) void*)g,
      (__attribute__((address_space(3))) void*)l, 16, 0, 0);
}
// counted-vmcnt barrier: own stage tile drained, next stage's 4 loads stay in flight
#define WAITB4 do { asm volatile("s_waitcnt vmcnt(4)" ::: "memory"); \
  __builtin_amdgcn_sched_barrier(0); __builtin_amdgcn_s_barrier(); \
  __builtin_amdgcn_sched_barrier(0); } while(0)
#define WAITB0 do { asm volatile("s_waitcnt vmcnt(0)" ::: "memory"); \
  __builtin_amdgcn_sched_barrier(0); __builtin_amdgcn_s_barrier(); \
  __builtin_amdgcn_sched_barrier(0); } while(0)

// ---------------- weight split ----------------
// Wf16: qkv@0 (196608), gate@196608 (65536), down@262144 (32768), up@294912 (32768) -- f16
// proj -> f16 hi/lo PAIR planes (65536 each)
__global__ __launch_bounds__(256) void wsplit_kernel(
    const float* __restrict__ wqkv, const float* __restrict__ wgate,
    const float* __restrict__ wdown, const float* __restrict__ wup,
    const float* __restrict__ wproj,
    unsigned short* __restrict__ Wf16,
    unsigned short* __restrict__ PH, unsigned short* __restrict__ PLo)
{
  int idx = blockIdx.x * 256 + threadIdx.x;   // 0..393215
  if (idx < 327680) {
    float s;
    if (idx < 196608)      s = wqkv[idx];
    else if (idx < 262144) s = wgate[idx - 196608];
    else if (idx < 294912) s = wdown[idx - 262144];
    else                   s = wup[idx - 294912];
    Wf16[idx] = f16b(s);
  } else {
    int j = idx - 327680;
    float wv = wproj[j];
    unsigned short hh = f16b(wv);
    PH[j]  = hh;
    PLo[j] = f16b(wv - f16tof(hh));
  }
}

// ---------------- x [b][c][l] fp32 -> xT hi/lo f16 [b][l][c] ----------------
__global__ __launch_bounds__(256) void splitx_kernel(const float* __restrict__ x,
    unsigned short* __restrict__ XThi, unsigned short* __restrict__ XTlo)
{
  __shared__ float st[64][68];
  const int b = blockIdx.z, c0 = blockIdx.y * 64, lb = blockIdx.x * 64;
  const int t = threadIdx.x;
  #pragma unroll
  for (int i = 0; i < 4; i++) {
    int row = (t >> 4) + i * 16;
    int col = (t & 15) * 4;
    float4 v = *(const float4*)&x[((size_t)b * C + c0 + row) * L + lb + col];
    st[row][col] = v.x; st[row][col+1] = v.y; st[row][col+2] = v.z; st[row][col+3] = v.w;
  }
  __syncthreads();
  const int l = t >> 2, cq = t & 3;
  u16x8 hv0, hv1, lv0, lv1;
  #pragma unroll
  for (int i = 0; i < 16; i++) {
    unsigned int p = splitpackh(st[cq * 16 + i][l]);
    if (i < 8) { hv0[i] = (unsigned short)(p & 0xFFFFu); lv0[i] = (unsigned short)(p >> 16); }
    else       { hv1[i-8] = (unsigned short)(p & 0xFFFFu); lv1[i-8] = (unsigned short)(p >> 16); }
  }
  size_t o = ((size_t)b * L + lb + l) * C + c0 + cq * 16;
  *(u16x8*)&XThi[o]     = hv0;
  *(u16x8*)&XThi[o + 8] = hv1;
  *(u16x8*)&XTlo[o]     = lv0;
  *(u16x8*)&XTlo[o + 8] = lv1;
}

// ---------------- f16 MFMA GEMM (qkv only), 2-phase double-buffered ----------------
template<int KTOT, int EPI, int MODE>
__global__ __launch_bounds__(256) void hgemm(
    const unsigned short* __restrict__ Ahi_g, const unsigned short* __restrict__ Alo_g,
    const unsigned short* __restrict__ Bw_g,
    float* __restrict__ outF,
    unsigned short* __restrict__ outH,
    int Ntot)
{
  __shared__ unsigned short SB[2][3][128 * 32];
  const int t  = threadIdx.x;
  const int lb = blockIdx.x * 128;
  const int o0 = blockIdx.y * 128;
  const int b  = blockIdx.z;
  const int w  = t >> 6, lane = t & 63;
  const int wm = w >> 1, wn = w & 1;
  const int ln = lane & 15, lg = lane >> 4;
  const int lrow  = lane >> 2;
  const int chunk = (lane & 3) ^ ((lane >> 4) & 3);
  const int slot  = lg ^ (ln >> 2);
  const bool twop = (blockIdx.y < 2);

  f32x4 z4 = {0.f, 0.f, 0.f, 0.f};
  f32x4 acc[4][4];
  #pragma unroll
  for (int i = 0; i < 4; i++)
    #pragma unroll
    for (int j = 0; j < 4; j++) acc[i][j] = z4;

  const size_t arow0 = (size_t)b * L + lb;
  constexpr int NKT = KTOT / 32;

  auto stage = [&](int kt, int cb) {
    const int k0 = kt * 32;
    #pragma unroll
    for (int i = 0; i < 2; i++) {
      const int rb = w * 32 + i * 16;
      const size_t ga = (arow0 + rb + lrow) * KTOT + k0 + chunk * 8;
      gl16(Ahi_g + ga, &SB[cb][0][rb * 32]);
      if (twop) gl16(Alo_g + ga, &SB[cb][1][rb * 32]);
      const size_t gb = (size_t)(o0 + rb + lrow) * KTOT + k0 + chunk * 8;
      gl16(Bw_g + gb, &SB[cb][2][rb * 32]);
    }
  };

  stage(0, 0);
  __syncthreads();
  int cur = 0;
  for (int kt = 0; kt < NKT; ++kt) {
    if (kt + 1 < NKT) stage(kt + 1, cur ^ 1);
    short8v bwf[4];
    #pragma unroll
    for (int nf = 0; nf < 4; nf++) {
      const int off = (wn * 64 + nf * 16 + ln) * 32 + slot * 8;
      bwf[nf] = *(const short8v*)&SB[cur][2][off];
    }
    #pragma unroll
    for (int mf = 0; mf < 4; mf++) {
      const int off = (wm * 64 + mf * 16 + ln) * 32 + slot * 8;
      const short8v ah = *(const short8v*)&SB[cur][0][off];
      #pragma unroll
      for (int nf = 0; nf < 4; nf++)
        acc[mf][nf] = __builtin_amdgcn_mfma_f32_16x16x32_f16(ah, bwf[nf], acc[mf][nf], 0, 0, 0);
      if (twop) {
        const short8v al = *(const short8v*)&SB[cur][1][off];
        #pragma unroll
        for (int nf = 0; nf < 4; nf++)
          acc[mf][nf] = __builtin_amdgcn_mfma_f32_16x16x32_f16(al, bwf[nf], acc[mf][nf], 0, 0, 0);
      }
    }
    __syncthreads();
    cur ^= 1;
  }
  #pragma unroll
  for (int mf = 0; mf < 4; mf++) {
    const int mbase = lb + wm * 64 + mf * 16 + lg * 4;
    #pragma unroll
    for (int nf = 0; nf < 4; nf++) {
      const int o = o0 + wn * 64 + nf * 16 + ln;
      if (o0 < 256) {
        float4 r;
        r.x = acc[mf][nf][0]; r.y = acc[mf][nf][1];
        r.z = acc[mf][nf][2]; r.w = acc[mf][nf][3];
        *(float4*)&outF[((size_t)b * 256 + o) * L + mbase] = r;
      } else {
        ushort4 r;
        r.x = f16b(acc[mf][nf][0]); r.y = f16b(acc[mf][nf][1]);
        r.z = f16b(acc[mf][nf][2]); r.w = f16b(acc[mf][nf][3]);
        *(ushort4*)&outH[((size_t)b * 512 + (o - 256)) * L + mbase] = r;
      }
    }
  }
}

// ---------------- FUSED MLP + PROJ v5: counted-vmcnt, 3-buffer depth-1 pipeline ----------------
// R12 v3 skeleton (static 32 stage lines, wave-local rows, verified bit-identical) with:
//  - wL[3] (stage s -> buf s%3; line s issues s+1 -> (s+1)%3; prior occupant s-2 retired)
//  - mL aliases zL rows 0-31 (R11-verified; __syncthreads guards the two clobber points)
//  - per-stage: issue(s+1); vmcnt(4); s_barrier; gemm(s)  -- next tile stays in flight (T4)
__global__ __launch_bounds__(256, 2) void mlp_fused_kernel(
    const unsigned short* __restrict__ zT,     // [b][l][256] f16
    const unsigned short* __restrict__ outT,   // [b][l][256] f16
    const unsigned short* __restrict__ Wg,     // [256][256] f16
    const unsigned short* __restrict__ Wd,     // [128][256] f16
    const unsigned short* __restrict__ Wu,     // [256][128] f16
    const unsigned short* __restrict__ WpH,    // [256][256] f16 hi
    const unsigned short* __restrict__ WpL,    // [256][256] f16 lo
    const float* __restrict__ bg, const float* __restrict__ bd, const float* __restrict__ bu,
    float* __restrict__ out0)                  // [b][256][L] fp32
{
  __shared__ unsigned short zL[64 * 256];      // 32KB
  __shared__ unsigned short wL[3][64 * 128];   // 3 x 16KB
  unsigned short* mL = zL;                     // [64][128] alias (barrier-guarded)
  const int t = threadIdx.x;
  const int l0 = blockIdx.x * 64;
  const int b  = blockIdx.y;
  const int w = t >> 6, lane = t & 63;
  const int ln = lane & 15, lg = lane >> 4;

  // ---- z tile: wave-local rows, pre-swizzled source, linear gl16 dest (8 gl16/wave) ----
  {
    const int rIn = lane >> 5, ch = lane & 31;
    #pragma unroll
    for (int j = 0; j < 8; j++) {
      const int rowbase = w * 16 + j * 2;
      const int row = rowbase + rIn;
      const int sc = ch ^ (row & 7);
      gl16(zT + ((size_t)b * L + l0 + row) * 256 + sc * 8, &zL[rowbase * 256]);
    }
  }
  // issue one [64][128] weight tile into wL[cb] (4 gl16/wave)
  auto issueW = [&](int cb, const unsigned short* src, int rowstride) {
    const int rIn = lane >> 4, ch = lane & 15;
    #pragma unroll
    for (int j = 0; j < 4; j++) {
      const int rowbase = j * 16 + w * 4;
      const int row = rowbase + rIn;
      const int sc = ch ^ (row & 7);
      gl16(src + (size_t)row * rowstride + sc * 8, &wL[cb][rowbase * 128]);
    }
  };
  auto fragZ = [&](int row, int cc) -> short8v {
    return *(const short8v*)&zL[row * 256 + (cc ^ (row & 7)) * 8];
  };
  auto fragW = [&](int cb, int row, int cc) -> short8v {
    return *(const short8v*)&wL[cb][row * 128 + (cc ^ (row & 7)) * 8];
  };
  auto fragM = [&](int row, int cc) -> short8v {
    return *(const short8v*)&mL[row * 128 + (cc ^ (row & 7)) * 8];
  };
  // one stage gemm: 64l x 64o x K128, wave w owns rows [w*16, w*16+16)
  auto gemmZt = [&](f32x4 (&acc)[4], int buf, int cbase) {
    #pragma unroll
    for (int ks = 0; ks < 4; ks++) {
      const short8v af = fragZ(w * 16 + ln, cbase + ks * 4 + lg);
      #pragma unroll
      for (int nf = 0; nf < 4; nf++) {
        const short8v bf = fragW(buf, nf * 16 + ln, ks * 4 + lg);
        acc[nf] = __builtin_amdgcn_mfma_f32_16x16x32_f16(af, bf, acc[nf], 0, 0, 0);
      }
    }
  };
  auto gemmMt = [&](f32x4 (&acc)[4], int buf) {
    #pragma unroll
    for (int ks = 0; ks < 4; ks++) {
      const short8v af = fragM(w * 16 + ln, ks * 4 + lg);
      #pragma unroll
      for (int nf = 0; nf < 4; nf++) {
        const short8v bf = fragW(buf, nf * 16 + ln, ks * 4 + lg);
        acc[nf] = __builtin_amdgcn_mfma_f32_16x16x32_f16(af, bf, acc[nf], 0, 0, 0);
      }
    }
  };

  const f32x4 zz = {0.f, 0.f, 0.f, 0.f};
  // prologue: s0 -> buf0; first WAITB4 drains z(8) + s0(4), leaves s1(4) in flight
  issueW(0, Wg, 256);

  // ---- gate: stages 0-7 ----
  f32x4 aG[4][4];
  #pragma unroll
  for (int i = 0; i < 4; i++)
    #pragma unroll
    for (int j = 0; j < 4; j++) aG[i][j] = zz;
  issueW(1, Wg + 128,           256); WAITB4; gemmZt(aG[0], 0, 0);
  issueW(2, Wg + 64*256,        256); WAITB4; gemmZt(aG[0], 1, 16);
  issueW(0, Wg + 64*256 + 128,  256); WAITB4; gemmZt(aG[1], 2, 0);
  issueW(1, Wg + 128*256,       256); WAITB4; gemmZt(aG[1], 0, 16);
  issueW(2, Wg + 128*256 + 128, 256); WAITB4; gemmZt(aG[2], 1, 0);
  issueW(0, Wg + 192*256,       256); WAITB4; gemmZt(aG[2], 2, 16);
  issueW(1, Wg + 192*256 + 128, 256); WAITB4; gemmZt(aG[3], 0, 0);
  issueW(2, Wd,                 256); WAITB4; gemmZt(aG[3], 1, 16);
  // gate epilogue (wave-local rows; no barrier)
  #pragma unroll
  for (int oc = 0; oc < 4; oc++)
    #pragma unroll
    for (int nf = 0; nf < 4; nf++)
      #pragma unroll
      for (int r = 0; r < 4; r++) {
        const int l = w * 16 + lg * 4 + r;
        const int o = oc * 64 + nf * 16 + ln;
        const int a = l * 256 + (((o >> 3) ^ (l & 7)) << 3) + (o & 7);
        zL[a] = f16b(gelu_exact(aG[oc][nf][r] + bg[o]) * f16tof(zL[a]));
      }
  // ---- down: stages 8-11 ----
  f32x4 aD[2][4];
  #pragma unroll
  for (int i = 0; i < 2; i++)
    #pragma unroll
    for (int j = 0; j < 4; j++) aD[i][j] = zz;
  issueW(0, Wd + 128,           256); WAITB4; gemmZt(aD[0], 2, 0);
  issueW(1, Wd + 64*256,        256); WAITB4; gemmZt(aD[0], 0, 16);
  issueW(2, Wd + 64*256 + 128,  256); WAITB4; gemmZt(aD[1], 1, 0);
  issueW(0, Wu,                 128); WAITB4; gemmZt(aD[1], 2, 16);
  __syncthreads();   // all gated reads done before mL (zL-alias) writes
  // down epilogue -> mL (wave-local rows of mL)
  #pragma unroll
  for (int oc = 0; oc < 2; oc++)
    #pragma unroll
    for (int nf = 0; nf < 4; nf++)
      #pragma unroll
      for (int r = 0; r < 4; r++) {
        const int l = w * 16 + lg * 4 + r;
        const int o = oc * 64 + nf * 16 + ln;
        mL[l * 128 + (((o >> 3) ^ (l & 7)) << 3) + (o & 7)] = f16b(aD[oc][nf][r] + bd[o]);
      }
  // ---- up: stages 12-15 ----
  f32x4 aU[4][4];
  #pragma unroll
  for (int i = 0; i < 4; i++)
    #pragma unroll
    for (int j = 0; j < 4; j++) aU[i][j] = zz;
  issueW(1, Wu + 64*128,        128); WAITB4; gemmMt(aU[0], 0);
  issueW(2, Wu + 128*128,       128); WAITB4; gemmMt(aU[1], 1);
  issueW(0, Wu + 192*128,       128); WAITB4; gemmMt(aU[2], 2);
  issueW(1, WpH,                256); WAITB4; gemmMt(aU[3], 0);
  __syncthreads();   // all mL reads done before preproj (zL) writes clobber alias
  // up epilogue: preproj = aU + bu + outT, overwrite zL (wave-local)
  #pragma unroll
  for (int oc = 0; oc < 4; oc++)
    #pragma unroll
    for (int nf = 0; nf < 4; nf++)
      #pragma unroll
      for (int r = 0; r < 4; r++) {
        const int l = w * 16 + lg * 4 + r;
        const int o = oc * 64 + nf * 16 + ln;
        const float v = aU[oc][nf][r] + bu[o]
                      + f16tof(outT[((size_t)b * L + l0 + l) * 256 + o]);
        zL[l * 256 + (((o >> 3) ^ (l & 7)) << 3) + (o & 7)] = f16b(v);
      }
  // ---- proj: stages 16-31 (2-pass f16-pair weights) ----
  f32x4 aP[4][4];
  #pragma unroll
  for (int i = 0; i < 4; i++)
    #pragma unroll
    for (int j = 0; j < 4; j++) aP[i][j] = zz;
  issueW(2, WpL,                256); WAITB4; gemmZt(aP[0], 1, 0);
  issueW(0, WpH + 128,          256); WAITB4; gemmZt(aP[0], 2, 0);
  issueW(1, WpL + 128,          256); WAITB4; gemmZt(aP[0], 0, 16);
  issueW(2, WpH + 64*256,       256); WAITB4; gemmZt(aP[0], 1, 16);
  issueW(0, WpL + 64*256,       256); WAITB4; gemmZt(aP[1], 2, 0);
  issueW(1, WpH + 64*256 + 128, 256); WAITB4; gemmZt(aP[1], 0, 0);
  issueW(2, WpL + 64*256 + 128, 256); WAITB4; gemmZt(aP[1], 1, 16);
  issueW(0, WpH + 128*256,      256); WAITB4; gemmZt(aP[1], 2, 16);
  issueW(1, WpL + 128*256,      256); WAITB4; gemmZt(aP[2], 0, 0);
  issueW(2, WpH + 128*256 + 128,256); WAITB4; gemmZt(aP[2], 1, 0);
  issueW(0, WpL + 128*256 + 128,256); WAITB4; gemmZt(aP[2], 2, 16);
  issueW(1, WpH + 192*256,      256); WAITB4; gemmZt(aP[2], 0, 16);
  issueW(2, WpL + 192*256,      256); WAITB4; gemmZt(aP[3], 1, 0);
  issueW(0, WpH + 192*256 + 128,256); WAITB4; gemmZt(aP[3], 2, 0);
  issueW(1, WpL + 192*256 + 128,256); WAITB4; gemmZt(aP[3], 0, 16);
                                      WAITB0; gemmZt(aP[3], 1, 16);
  // proj write
  #pragma unroll
  for (int oc = 0; oc < 4; oc++)
    #pragma unroll
    for (int nf = 0; nf < 4; nf++) {
      const int o = oc * 64 + nf * 16 + ln;
      float4 r4;
      r4.x = aP[oc][nf][0]; r4.y = aP[oc][nf][1];
      r4.z = aP[oc][nf][2]; r4.w = aP[oc][nf][3];
      *(float4*)&out0[((size_t)b * 256 + o) * L + l0 + w * 16 + lg * 4] = r4;
    }
}

// ---------------- depthwise 3x3 conv: q from fp32, k/v from f16; out single f16 ----------------
__global__ __launch_bounds__(256) void dwconv2_kernel(
    const float* __restrict__ inQ, const unsigned short* __restrict__ inKV,
    const float* __restrict__ wdw,
    unsigned short* __restrict__ qkF, unsigned short* __restrict__ vF,
    float* __restrict__ csum, float* __restrict__ csumsq)
{
  __shared__ float p[66][73];
  __shared__ float rs[4][2];
  const int ch = blockIdx.x;
  const int b  = blockIdx.y;
  const int t  = threadIdx.x;
  float wt[9];
  #pragma unroll
  for (int j = 0; j < 9; j++) wt[j] = wdw[ch * 9 + j];
  if (t < 66) { p[0][3 + t] = 0.f; p[65][3 + t] = 0.f; }
  if (t < 64) { p[1 + t][3] = 0.f; p[1 + t][68] = 0.f; }
  if (ch < 256) {
    const size_t base = ((size_t)b * 256 + ch) * L;
    #pragma unroll
    for (int i = 0; i < 4; i++) {
      int pix = (i * 256 + t) * 4;
      const float4 v = *reinterpret_cast<const float4*>(&inQ[base + pix]);
      int h = pix >> 6, ww = pix & 63;
      p[1+h][4+ww] = v.x; p[1+h][5+ww] = v.y; p[1+h][6+ww] = v.z; p[1+h][7+ww] = v.w;
    }
  } else {
    const size_t base = ((size_t)b * 512 + (ch - 256)) * L + t * 16;
    const u16x8 a0 = *(const u16x8*)&inKV[base];
    const u16x8 a1 = *(const u16x8*)&inKV[base + 8];
    const int h = t >> 2, w0 = (t & 3) * 16;
    #pragma unroll
    for (int j = 0; j < 8; j++) {
      p[1+h][4+w0+j]   = f16tof((unsigned short)a0[j]);
      p[1+h][12+w0+j]  = f16tof((unsigned short)a1[j]);
    }
  }
  __syncthreads();
  const int h  = t >> 2;
  const int w0 = (t & 3) * 16;
  float r0a[18], r1a[18], r2a[18];
  #pragma unroll
  for (int c = 0; c < 18; c++) {
    r0a[c] = p[h][w0 + 3 + c];
    r1a[c] = p[h + 1][w0 + 3 + c];
    r2a[c] = p[h + 2][w0 + 3 + c];
  }
  float res[16];
  float s = 0.f, s2 = 0.f;
  #pragma unroll
  for (int j = 0; j < 16; j++) {
    float acc;
    acc = r0a[j] * wt[0];
    acc = fmaf(r0a[j+1], wt[1], acc);
    acc = fmaf(r0a[j+2], wt[2], acc);
    acc = fmaf(r1a[j],   wt[3], acc);
    acc = fmaf(r1a[j+1], wt[4], acc);
    acc = fmaf(r1a[j+2], wt[5], acc);
    acc = fmaf(r2a[j],   wt[6], acc);
    acc = fmaf(r2a[j+1], wt[7], acc);
    acc = fmaf(r2a[j+2], wt[8], acc);
    res[j] = acc;
    s += acc;
    s2 = fmaf(acc, acc, s2);
  }
  u16x8 h0v, h1v;
  #pragma unroll
  for (int j = 0; j < 16; j++) {
    if (j < 8) h0v[j]   = f16b(res[j]);
    else       h1v[j-8] = f16b(res[j]);
  }
  if (ch < 512) {
    const size_t qi = ((size_t)b * 512 + ch) * L + t * 16;
    *(u16x8*)&qkF[qi]     = h0v;
    *(u16x8*)&qkF[qi + 8] = h1v;
    s = wave_sum(s); s2 = wave_sum(s2);
    const int lane = t & 63, wid = t >> 6;
    if (lane == 0) { rs[wid][0] = s; rs[wid][1] = s2; }
    __syncthreads();
    if (t == 0) {
      csum[b * 512 + ch]   = rs[0][0] + rs[1][0] + rs[2][0] + rs[3][0];
      csumsq[b * 512 + ch] = rs[0][1] + rs[1][1] + rs[2][1] + rs[3][1];
    }
  } else {
    const size_t vi = ((size_t)b * 256 + (ch - 512)) * L + t * 16;
    *(u16x8*)&vF[vi]     = h0v;
    *(u16x8*)&vF[vi + 8] = h1v;
  }
}

// ---------------- rank (stable descending) + sorted stats ----------------
__global__ __launch_bounds__(256) void rankstats_kernel(
    const float* __restrict__ csum, const float* __restrict__ csumsq,
    int* __restrict__ order,
    float* __restrict__ sumq, float* __restrict__ sumk,
    float* __restrict__ invnq, float* __restrict__ invnk)
{
  const int c = threadIdx.x;
  float key = 0.f;
  #pragma unroll
  for (int b = 0; b < 8; b++) key += csum[b * 512 + c];
  __shared__ float keys[256];
  __shared__ int ordS[256];
  keys[c] = key;
  __syncthreads();
  int rank = 0;
  for (int j = 0; j < 256; j++) {
    float kj = keys[j];
    rank += (kj > key) || (kj == key && j < c);
  }
  order[rank] = c;
  ordS[rank] = c;
  __syncthreads();
  const int ch = ordS[c];
  #pragma unroll
  for (int b = 0; b < 8; b++) {
    sumq[b * 256 + c]  = csum[b * 512 + ch];
    invnq[b * 256 + c] = 1.0f / fmaxf(sqrtf(csumsq[b * 512 + ch]), 1e-12f);
    sumk[b * 256 + c]  = csum[b * 512 + 256 + ch];
    invnk[b * 256 + c] = 1.0f / fmaxf(sqrtf(csumsq[b * 512 + 256 + ch]), 1e-12f);
  }
}

// ---------------- pack: vTS = v^T sorted (f16) [b][l][r]; zqT = qn+kn (f16) [b][l][r] ----------------
__global__ __launch_bounds__(256) void vpack_kernel(
    const unsigned short* __restrict__ vF, const unsigned short* __restrict__ qkF,
    const int* __restrict__ order,
    const float* __restrict__ invnq, const float* __restrict__ invnk,
    unsigned short* __restrict__ vTS, unsigned short* __restrict__ zqT)
{
  __shared__ float vt[64][65];
  __shared__ float zt[64][65];
  __shared__ int   ordS[256];
  __shared__ float iqS[256], ikS[256];
  const int t = threadIdx.x, lb = blockIdx.x * 64, b = blockIdx.y;
  ordS[t] = order[t];
  iqS[t] = invnq[b * 256 + t];
  ikS[t] = invnk[b * 256 + t];
  __syncthreads();
  for (int cc = 0; cc < 4; cc++) {
    const int r0 = cc * 64;
    for (int i = t; i < 1024; i += 256) {
      const int row = i >> 4, q = i & 15;
      const int ch = ordS[r0 + row];
      const float iq = iqS[r0 + row], ik = ikS[r0 + row];
      const ushort4 v4 = *(const ushort4*)&vF[((size_t)b * 256 + ch) * L + lb + q * 4];
      vt[q*4+0][row] = f16tof(v4.x); vt[q*4+1][row] = f16tof(v4.y);
      vt[q*4+2][row] = f16tof(v4.z); vt[q*4+3][row] = f16tof(v4.w);
      const ushort4 q4 = *(const ushort4*)&qkF[((size_t)b * 512 + ch) * L + lb + q * 4];
      const ushort4 k4 = *(const ushort4*)&qkF[((size_t)b * 512 + 256 + ch) * L + lb + q * 4];
      zt[q*4+0][row] = f16tof(q4.x) * iq + f16tof(k4.x) * ik;
      zt[q*4+1][row] = f16tof(q4.y) * iq + f16tof(k4.y) * ik;
      zt[q*4+2][row] = f16tof(q4.z) * iq + f16tof(k4.z) * ik;
      zt[q*4+3][row] = f16tof(q4.w) * iq + f16tof(k4.w) * ik;
    }
    __syncthreads();
    const int l = t >> 2, qq = t & 3;
    const size_t ob = ((size_t)b * L + lb + l) * 256 + r0 + qq * 16;
    u16x8 vv[2], zz[2];
    #pragma unroll
    for (int j = 0; j < 16; j++) {
      vv[j>>3][j&7] = f16b(vt[l][qq*16 + j]);
      zz[j>>3][j&7] = f16b(zt[l][qq*16 + j]);
    }
    *(u16x8*)&vTS[ob]     = vv[0]; *(u16x8*)&vTS[ob + 8] = vv[1];
    *(u16x8*)&zqT[ob]     = zz[0]; *(u16x8*)&zqT[ob + 8] = zz[1];
    __syncthreads();
  }
}

// ---------------- scores via 1-pass f16 MFMA, 2-phase gather staging ----------------
template<int G, int GI, int START, int MB, int SPB>
__device__ void scores_body(const unsigned short* __restrict__ qkF,
    const int* __restrict__ order, float* __restrict__ Spart,
    unsigned short* Ah, unsigned short* Bh, int* ordS)
{
  constexpr int MR = (G - MB * 64 < 64) ? (G - MB * 64) : 64;
  constexpr int NF = G / 16;
  const int t = threadIdx.x, ks = blockIdx.x, b = blockIdx.y;
  const int w = t >> 6, lane = t & 63, ln = lane & 15, lg = lane >> 4;
  const int lrow  = lane >> 2;
  const int chunk = (lane & 3) ^ ((lane >> 4) & 3);
  const int slot  = lg ^ (ln >> 2);
  for (int i = t; i < G; i += 256) ordS[i] = order[START + i];
  __syncthreads();
  const int k0 = ks * 512;
  const bool act = (w * 16) < MR;
  f32x4 z4 = {0.f, 0.f, 0.f, 0.f};
  f32x4 acc[NF];
  #pragma unroll
  for (int i = 0; i < NF; i++) acc[i] = z4;

  auto stage = [&](int kc, int cb) {
    for (int i = w; i < MR / 16; i += 4) {
      const int rb = i * 16;
      const int ch = ordS[MB * 64 + rb + lrow];
      const size_t g = ((size_t)b * 512 + ch) * L + k0 + kc + chunk * 8;
      gl16(qkF + g, &Ah[cb * 2048 + rb * 32]);
    }
    for (int i = w; i < G / 16; i += 4) {
      const int rb = i * 16;
      const int ch = 256 + ordS[rb + lrow];
      const size_t g = ((size_t)b * 512 + ch) * L + k0 + kc + chunk * 8;
      gl16(qkF + g, &Bh[cb * 3072 + rb * 32]);
    }
  };

  stage(0, 0);
  __syncthreads();
  int cur = 0;
  for (int kc = 0; kc < 512; kc += 32) {
    if (kc + 32 < 512) stage(kc + 32, cur ^ 1);
    if (act) {
      const int aoff = cur * 2048 + (w * 16 + ln) * 32 + slot * 8;
      const short8v ah = *(const short8v*)&Ah[aoff];
      #pragma unroll
      for (int nf = 0; nf < NF; nf++) {
        const int boff = cur * 3072 + (nf * 16 + ln) * 32 + slot * 8;
        const short8v bh = *(const short8v*)&Bh[boff];
        acc[nf] = __builtin_amdgcn_mfma_f32_16x16x32_f16(ah, bh, acc[nf], 0, 0, 0);
      }
    }
    __syncthreads();
    cur ^= 1;
  }
  if (act) {
    float* dst = Spart + (size_t)b * 147456 + SPB + ks * G * G;
    #pragma unroll
    for (int nf = 0; nf < NF; nf++) {
      const int d = nf * 16 + ln;
      #pragma unroll
      for (int r = 0; r < 4; r++) {
        const int m = MB * 64 + w * 16 + lg * 4 + r;
        dst[m * G + d] = acc[nf][r];
      }
    }
  }
}

__global__ __launch_bounds__(256) void scores_kernel(const unsigned short* __restrict__ qkF,
    const int* __restrict__ order, float* __restrict__ Spart)
{
  __shared__ unsigned short Ah[2 * 64 * 32];
  __shared__ unsigned short Bh[2 * 96 * 32];
  __shared__ int ordS[96];
  switch (blockIdx.z) {
    case 0:  scores_body<32, 0, 0,   0, 0    >(qkF, order, Spart, Ah, Bh, ordS); break;
    case 1:  scores_body<64, 1, 32,  0, 8192 >(qkF, order, Spart, Ah, Bh, ordS); break;
    case 2:  scores_body<64, 2, 96,  0, 40960>(qkF, order, Spart, Ah, Bh, ordS); break;
    case 3:  scores_body<96, 3, 160, 0, 73728>(qkF, order, Spart, Ah, Bh, ordS); break;
    default: scores_body<96, 3, 160, 1, 73728>(qkF, order, Spart, Ah, Bh, ordS); break;
  }
}

// ---------------- reduce partials, scale, wave-parallel softmax -> single f16 attn ----------------
template<int G, int GI, int START, int SPB, int AOFF>
__device__ void softmax_body(const float* __restrict__ Spart, const float* __restrict__ invnq,
    const float* __restrict__ invnk, const float* __restrict__ temperature,
    unsigned short* __restrict__ attnP, float* Sm)
{
  constexpr int RQ = G / 4;
  const int t = threadIdx.x;
  const int b = blockIdx.x;
  const int r0 = blockIdx.z * RQ;
  const float temp = temperature[GI];
  for (int idx = t; idx < RQ * G; idx += 256) {
    const int rl = idx / G, d = idx - rl * G;
    const int gidx = (r0 + rl) * G + d;
    float s = 0.f;
    #pragma unroll
    for (int ks = 0; ks < 8; ks++)
      s += Spart[(size_t)b * 147456 + SPB + ks * G * G + gidx];
    Sm[idx] = s * invnq[b * 256 + START + r0 + rl] * invnk[b * 256 + START + d] * temp;
  }
  __syncthreads();
  const int wv = t >> 6, lane = t & 63;
  for (int r = wv; r < RQ; r += 4) {
    const float v0 = (lane < G) ? Sm[r * G + lane] : -INFINITY;
    const float v1 = (64 + lane < G) ? Sm[r * G + 64 + lane] : -INFINITY;
    float m = fmaxf(v0, v1);
    #pragma unroll
    for (int off = 32; off > 0; off >>= 1) m = fmaxf(m, __shfl_xor(m, off, 64));
    const float e0 = (lane < G) ? expf(v0 - m) : 0.f;
    const float e1 = (64 + lane < G) ? expf(v1 - m) : 0.f;
    float s = e0 + e1;
    #pragma unroll
    for (int off = 32; off > 0; off >>= 1) s += __shfl_xor(s, off, 64);
    const float inv = 1.0f / s;
    const size_t base = (size_t)b * 18432 + AOFF + (size_t)(r0 + r) * G;
    if (lane < G)      attnP[base + lane]      = f16b(e0 * inv);
    if (64 + lane < G) attnP[base + 64 + lane] = f16b(e1 * inv);
  }
}

__global__ __launch_bounds__(256) void softmax_kernel(const float* __restrict__ Spart,
    const float* __restrict__ invnq, const float* __restrict__ invnk,
    const float* __restrict__ temperature, unsigned short* __restrict__ attnP)
{
  extern __shared__ float smem[];
  switch (blockIdx.y) {
    case 0:  softmax_body<32, 0, 0,   0,     0   >(Spart, invnq, invnk, temperature, attnP, smem); break;
    case 1:  softmax_body<64, 1, 32,  8192,  1024>(Spart, invnq, invnk, temperature, attnP, smem); break;
    case 2:  softmax_body<64, 2, 96,  40960, 5120>(Spart, invnq, invnk, temperature, attnP, smem); break;
    default: softmax_body<96, 3, 160, 73728, 9216>(Spart, invnq, invnk, temperature, attnP, smem); break;
  }
}

// ---------------- PV via 1-pass f16 MFMA, fused z epilogue -> single f16 ----------------
template<int G, int GI, int START, int AOFF>
__device__ void pv_body(
    const unsigned short* __restrict__ vTS, const unsigned short* __restrict__ attnP,
    const unsigned short* __restrict__ zqT,
    unsigned short* __restrict__ outT, unsigned short* __restrict__ zT,
    unsigned short* Ah, unsigned short* Bh)
{
  constexpr int NF = G / 16;
  const int t = threadIdx.x, b = blockIdx.y, l0 = blockIdx.x * 128;
  const int w = t >> 6, lane = t & 63, ln = lane & 15, lg = lane >> 4;
  const int lrow  = lane >> 2;
  const int chunk = (lane & 3) ^ ((lane >> 4) & 3);
  const int slot  = lg ^ (ln >> 2);
  f32x4 z4 = {0.f, 0.f, 0.f, 0.f};
  f32x4 acc[2][NF];
  #pragma unroll
  for (int i = 0; i < 2; i++)
    #pragma unroll
    for (int j = 0; j < NF; j++) acc[i][j] = z4;
  for (int kc = 0; kc < G; kc += 32) {
    #pragma unroll
    for (int i = 0; i < 2; i++) {
      const int rb = w * 32 + i * 16;
      const size_t g = ((size_t)b * L + l0 + rb + lrow) * 256 + START + kc + chunk * 8;
      gl16(vTS + g, &Ah[rb * 32]);
    }
    for (int i = w; i < G / 16; i += 4) {
      const int rb = i * 16;
      const size_t g = (size_t)b * 18432 + AOFF + (size_t)(rb + lrow) * G + kc + chunk * 8;
      gl16(attnP + g, &Bh[rb * 32]);
    }
    __syncthreads();
    short8v bhf[NF];
    #pragma unroll
    for (int nf = 0; nf < NF; nf++)
      bhf[nf] = *(const short8v*)&Bh[(nf * 16 + ln) * 32 + slot * 8];
    #pragma unroll
    for (int mi = 0; mi < 2; mi++) {
      const int aoff = ((w * 2 + mi) * 16 + ln) * 32 + slot * 8;
      const short8v ah = *(const short8v*)&Ah[aoff];
      #pragma unroll
      for (int nf = 0; nf < NF; nf++)
        acc[mi][nf] = __builtin_amdgcn_mfma_f32_16x16x32_f16(ah, bhf[nf], acc[mi][nf], 0, 0, 0);
    }
    __syncthreads();
  }
  #pragma unroll
  for (int mi = 0; mi < 2; mi++) {
    const int lbase = l0 + (w * 2 + mi) * 16 + lg * 4;
    #pragma unroll
    for (int nf = 0; nf < NF; nf++) {
      const int col = START + nf * 16 + ln;
      #pragma unroll
      for (int r = 0; r < 4; r++) {
        const size_t idx = ((size_t)b * L + lbase + r) * 256 + col;
        const float v = acc[mi][nf][r];
        outT[idx] = f16b(v);
        zT[idx]   = f16b(v + f16tof(zqT[idx]));
      }
    }
  }
}

__global__ __launch_bounds__(256) void pv_kernel(
    const unsigned short* __restrict__ vTS, const unsigned short* __restrict__ attnP,
    const unsigned short* __restrict__ zqT,
    unsigned short* __restrict__ outT, unsigned short* __restrict__ zT)
{
  __shared__ unsigned short Ah[128 * 32];
  __shared__ unsigned short Bh[96 * 32];
  switch (blockIdx.z) {
    case 0:  pv_body<32, 0, 0,   0   >(vTS, attnP, zqT, outT, zT, Ah, Bh); break;
    case 1:  pv_body<64, 1, 32,  1024>(vTS, attnP, zqT, outT, zT, Ah, Bh); break;
    case 2:  pv_body<64, 2, 96,  5120>(vTS, attnP, zqT, outT, zT, Ah, Bh); break;
    default: pv_body<96, 3, 160, 9216>(vTS, attnP, zqT, outT, zT, Ah, Bh); break;
  }
}

// ---------------- qv_cache ----------------
__global__ __launch_bounds__(256) void qv_kernel(const float* __restrict__ sumq,
    const float* __restrict__ sumk, const float* __restrict__ invnq,
    const float* __restrict__ invnk, float* __restrict__ out2)
{
  const int b = blockIdx.x >> 8, r = blockIdx.x & 255;
  float val = 0.f;
  {
    const int idx = b * 256 + 0 + (r & 31);
    val += fmaf(sumq[idx], invnq[idx], sumk[idx] * invnk[idx]);
  }
  {
    const int idx = b * 256 + 32 + (r & 63);
    val += fmaf(sumq[idx], invnq[idx], sumk[idx] * invnk[idx]);
  }
  {
    const int idx = b * 256 + 96 + (r & 63);
    val += fmaf(sumq[idx], invnq[idx], sumk[idx] * invnk[idx]);
  }
  if (r < 192) {
    const int rm = (r < 96) ? r : r - 96;
    const int idx = b * 256 + 160 + rm;
    val += fmaf(sumq[idx], invnq[idx], sumk[idx] * invnk[idx]);
  }
  val *= (1.0f / 4096.f) * 0.25f * 0.9f;
  const float4 o = {val, val, val, val};
  float4* dst = reinterpret_cast<float4*>(out2 + ((size_t)b * C + r) * L);
  for (int i = threadIdx.x; i < 1024; i += 256) dst[i] = o;
}

// ---------------- launch ----------------
extern "C" void kernel_launch(void* const* d_in, const int* in_sizes, int n_in,
                              void* d_out, int out_size, void* d_ws, size_t ws_size,
                              hipStream_t stream)
{
  const float* x           = (const float*)d_in[0];
  const float* temperature = (const float*)d_in[1];
  const float* w_qkv       = (const float*)d_in[2];
  const float* w_dw        = (const float*)d_in[3];
  const float* w_proj      = (const float*)d_in[4];
  const float* w_gate      = (const float*)d_in[5];
  const float* b_gate      = (const float*)d_in[6];
  const float* w_down      = (const float*)d_in[7];
  const float* b_down      = (const float*)d_in[8];
  const float* w_up        = (const float*)d_in[9];
  const float* b_up        = (const float*)d_in[10];

  if (ws_size < 202548224ULL) return;

  char* ws = (char*)d_ws;
  // Region A [0, 96M):
  float*          qkvQ    = (float*)(ws);                      // 32MB fp32 q (dead after conv)
  unsigned short* kvF     = (unsigned short*)(ws + 33554432);  // 32MB f16 k,v (dead after conv)
  unsigned short* vTS     = (unsigned short*)(ws);             // 16MB (after conv)
  unsigned short* zqT     = (unsigned short*)(ws + 16777216);  // 16MB
  float*          Spart   = (float*)(ws + 33554432);           // 4.72MB (after conv)
  unsigned short* attnP   = (unsigned short*)(ws + 38797312);  // 288KB
  // Region B [96M, 192M):
  unsigned short* XThi    = (unsigned short*)(ws + 100663296); // 16MB (dead after qkv)
  unsigned short* XTlo    = (unsigned short*)(ws + 117440512); // 16MB
  unsigned short* qkF     = (unsigned short*)(ws + 100663296); // 32MB (conv out)
  unsigned short* vF      = (unsigned short*)(ws + 134217728); // 16MB
  unsigned short* outT    = (unsigned short*)(ws + 150994944); // 16MB
  unsigned short* zT      = (unsigned short*)(ws + 167772160); // 16MB
  // Region C [192M+, persistent):
  unsigned short* Wf16   = (unsigned short*)(ws + 201326592);  // 655360B
  unsigned short* WprojH = (unsigned short*)(ws + 201981952);  // 128KB
  unsigned short* WprojL = (unsigned short*)(ws + 202113024);  // 128KB
  float* csum   = (float*)(ws + 202244096);
  float* csumsq = (float*)(ws + 202260480);
  float* sumq   = (float*)(ws + 202276864);
  float* sumk   = (float*)(ws + 202285056);
  float* invnq  = (float*)(ws + 202293248);
  float* invnk  = (float*)(ws + 202301440);
  int*   order  = (int*)(ws + 202309632);

  float* out_all = (float*)d_out;
  float* qv_out  = out_all + (size_t)B * C * L;

  // 0. weight + input splits
  wsplit_kernel<<<1536, 256, 0, stream>>>(w_qkv, w_gate, w_down, w_up, w_proj,
                                          Wf16, WprojH, WprojL);
  splitx_kernel<<<dim3(64, 4, 8), 256, 0, stream>>>(x, XThi, XTlo);
  // 1. qkv: q-blocks 2-pass -> fp32; k/v-blocks 1-pass -> f16
  hgemm<256, 6, 2><<<dim3(32, 6, 8), 256, 0, stream>>>(
      XThi, XTlo, Wf16, qkvQ, kvF, 768);
  // 2. depthwise conv (q fp32-in, k/v f16-in) -> qkF/vF single f16 + stats
  dwconv2_kernel<<<dim3(768, 8), 256, 0, stream>>>(qkvQ, kvF, w_dw, qkF, vF, csum, csumsq);
  // 3. channel ordering + sorted stats
  rankstats_kernel<<<1, 256, 0, stream>>>(csum, csumsq, order, sumq, sumk, invnq, invnk);
  // 4. pack v^T sorted + zq (single f16)
  vpack_kernel<<<dim3(64, 8), 256, 0, stream>>>(vF, qkF, order, invnq, invnk, vTS, zqT);
  // 5. attention (1-pass f16)
  scores_kernel<<<dim3(8, 8, 5), 256, 0, stream>>>(qkF, order, Spart);
  softmax_kernel<<<dim3(8, 4, 4), 256, 9216, stream>>>(Spart, invnq, invnk, temperature, attnP);
  pv_kernel<<<dim3(32, 8, 4), 256, 0, stream>>>(vTS, attnP, zqT, outT, zT);
  // 6. FUSED gate+down+up+proj (counted-vmcnt 3-buffer pipeline) -> output 0
  mlp_fused_kernel<<<dim3(64, 8), 256, 0, stream>>>(
      zT, outT, Wf16 + 196608, Wf16 + 262144, Wf16 + 294912, WprojH, WprojL,
      b_gate, b_down, b_up, out_all);
  // 7. qv_cache -> output 1
  qv_kernel<<<2048, 256, 0, stream>>>(sumq, sumk, invnq, invnk, qv_out);
}